// Round 16
// baseline (645.353 us; speedup 1.0000x reference)
//
#include <hip/hip_runtime.h>
#include <math.h>

constexpr int B_  = 2;
constexpr int T_  = 2048;
constexpr int D_  = 512;
constexpr int NH_ = 8;
constexpr int NL_ = 256;
constexpr int HN_ = NH_ * NL_;   // 2048
constexpr int BT_ = B_ * T_;     // 4096

typedef __bf16 v8bf __attribute__((ext_vector_type(8)));
typedef float  v4f  __attribute__((ext_vector_type(4)));
typedef unsigned short us8 __attribute__((ext_vector_type(8)));
typedef unsigned short us4 __attribute__((ext_vector_type(4)));

__device__ inline unsigned short f2b(float f) {
    union { float f; unsigned u; } v{f};
    unsigned r = v.u + 0x7FFF + ((v.u >> 16) & 1);   // rtne
    return (unsigned short)(r >> 16);
}
__device__ inline float b2f(unsigned short u) {
    union { unsigned u; float f; } v{(unsigned)u << 16};
    return v.f;
}

// async 16B global->LDS (per-lane gaddr; LDS dest = wave-uniform base + lane*16)
__device__ __forceinline__ void g2l16(const void* g, void* l) {
    __builtin_amdgcn_global_load_lds(
        (const __attribute__((address_space(1))) void*)g,
        (__attribute__((address_space(3))) void*)l, 16, 0, 0);
}

// counted waits (T4): never drain vmcnt to 0 mid-loop
#define VMCNT4 asm volatile("s_waitcnt vmcnt(4)" ::: "memory")
#define VMCNT2 asm volatile("s_waitcnt vmcnt(2)" ::: "memory")
#define VMCNT0 asm volatile("s_waitcnt vmcnt(0)" ::: "memory")
#define BARRIER_FENCE                                   \
    __builtin_amdgcn_s_barrier();                       \
    asm volatile("" ::: "memory")

// ===========================================================================
// Shared lane decomposition.
#define TILE_IDS                                              \
    int tid = threadIdx.x;                                    \
    int lane = tid & 63, wid = tid >> 6;                      \
    int wm = (wid & 1) * 64, wn = (wid >> 1) * 64;            \
    int ln16 = lane & 15, q = lane >> 4;                      \
    int srl = lane >> 2, scl = (lane & 3) * 8;                \
    (void)wm; (void)wn;

// 128x128 MFMA step: 4x4 16x16x32 per wave (16 MFMA).
#define TILE_MFMA(Asx, Bsx)                                   \
    {                                                         \
        v8bf af[4], bfr[4];                                   \
        _Pragma("unroll")                                     \
        for (int r = 0; r < 4; ++r)                           \
            af[r] = *(const v8bf*)&Asx[wm + r * 16 + ln16][q * 8]; \
        _Pragma("unroll")                                     \
        for (int c = 0; c < 4; ++c)                           \
            bfr[c] = *(const v8bf*)&Bsx[wn + c * 16 + ln16][q * 8]; \
        _Pragma("unroll")                                     \
        for (int r = 0; r < 4; ++r)                           \
            _Pragma("unroll")                                 \
            for (int c = 0; c < 4; ++c)                       \
                acc[r][c] = __builtin_amdgcn_mfma_f32_16x16x32_bf16( \
                    af[r], bfr[c], acc[r][c], 0, 0, 0);       \
    }

// ---------------------------------------------------------------------------
// Generic 128x128-tile bf16 GEMM, counted-vmcnt pipeline (T3+T4):
// BK=32, 3 LDS buffers (48 KB -> 3 blocks/CU), depth-2 prefetch.  Per step:
// wait own 4 loads of oldest tile (vmcnt in-order), barrier, issue
// stage(t+2), 16 MFMA.  stage(t+2) overwrites buf (t-1)%3 whose reads
// finished before barrier(t) on all waves -> race-free.  K order identical
// to 2-phase -> bitwise-identical accumulation.
// LNA: LN(A)@B = inv * (A@B - mu * colsum(B)) in the epilogue.
template <bool RELU, bool MUL, bool BF16OUT, bool LNA>
__global__ __launch_bounds__(256) void gemm128(
    const unsigned short* __restrict__ A, int lda, long sA,
    const unsigned short* __restrict__ Bt, int ldb, long sB,
    void* __restrict__ Cv, int ldc, long sC,
    const unsigned short* __restrict__ mulp, int K,
    const float* __restrict__ muinv, const float* __restrict__ colsum) {
    int m0 = blockIdx.y * 128, n0 = blockIdx.x * 128, z = blockIdx.z;
    __shared__ unsigned short As[3][128][32];   // 24 KB
    __shared__ unsigned short Bs[3][128][32];   // 24 KB
    const unsigned short* Ab = A  + (long)z * sA + (long)m0 * lda;
    const unsigned short* Bb = Bt + (long)z * sB + (long)n0 * ldb;
    TILE_IDS
    v4f acc[4][4] = {};
    int NT = K >> 5;
    auto stage = [&](int t, int buf) {
        int k0 = t * 32;
        #pragma unroll
        for (int ci = 0; ci < 4; ++ci) {
            int c = wid * 4 + ci;
            if (c < 8)
                g2l16(Ab + (long)(c * 16 + srl) * lda + k0 + scl,
                      (char*)As[buf] + c * 1024);
            else
                g2l16(Bb + (long)((c - 8) * 16 + srl) * ldb + k0 + scl,
                      (char*)Bs[buf] + (c - 8) * 1024);
        }
    };
    stage(0, 0);
    if (NT > 1) stage(1, 1);
    int bcur = 0, bnxt = 2;
    for (int t = 0; t < NT; ++t) {
        if (t + 1 < NT) { VMCNT4; } else { VMCNT0; }
        BARRIER_FENCE;
        if (t + 2 < NT) stage(t + 2, bnxt);
        TILE_MFMA(As[bcur], Bs[bcur])
        bcur = bcur + 1 == 3 ? 0 : bcur + 1;
        bnxt = bnxt + 1 == 3 ? 0 : bnxt + 1;
    }
    float* Cf = (float*)Cv;
    unsigned short* Cb = (unsigned short*)Cv;
    long zoff = (long)z * sC;
    #pragma unroll
    for (int r = 0; r < 4; ++r)
        #pragma unroll
        for (int c = 0; c < 4; ++c)
            #pragma unroll
            for (int e = 0; e < 4; ++e) {
                int row = m0 + wm + r * 16 + q * 4 + e;
                int col = n0 + wn + c * 16 + ln16;
                float v = acc[r][c][e];
                if (LNA) {
                    float2 mi = *(const float2*)&muinv[((long)z * BT_ + row) * 2];
                    float cs = colsum[(long)z * NL_ + col];
                    v = mi.y * (v - mi.x * cs);
                }
                if (RELU) v = fmaxf(v, 0.f);
                long idx = zoff + (long)row * ldc + col;
                if (MUL) v *= b2f(mulp[idx]);
                if (BF16OUT) Cb[idx] = f2b(v);
                else         Cf[idx] = v;
            }
}

// ---------------------------------------------------------------------------
// ENC+ROPE fused, 128x128 tile, counted-vmcnt pipeline (measured r15):
// BK=32, 4 LDS buffers (64 KB), depth-2 prefetch.  grid (16 nt, 32 mt).
// [r13 lesson: 128x64 tiles regressed — bandwidth/structure-bound.]
__global__ __launch_bounds__(256) void enc_rope(
    const unsigned short* __restrict__ A,    // xs_b [BT][512]
    const unsigned short* __restrict__ Bt,   // encT [HN][512] K-major
    unsigned short* __restrict__ xsp,        // [BT][HN]
    unsigned short* __restrict__ qrh,        // [z][T][NL]
    unsigned short* __restrict__ qrT) {      // [z][NL][T]
    int m0 = blockIdx.y * 128, n0 = blockIdx.x * 128;
    __shared__ unsigned short As[4][128][32];   // 32 KB (4 bufs x 8 KB)
    __shared__ unsigned short Bs[4][128][32];   // 32 KB
    unsigned short (*lt)[136] = (unsigned short(*)[136])&As[0][0][0]; // 34.8 KB
    const unsigned short* Ab = A + (long)m0 * 512;
    const unsigned short* Bb = Bt + (long)n0 * 512;
    TILE_IDS
    v4f acc[4][4] = {};
    auto stage = [&](int t) {
        int k0 = t * 32, buf = t & 3;
        #pragma unroll
        for (int ci = 0; ci < 4; ++ci) {
            int c = wid * 4 + ci;
            if (c < 8)
                g2l16(Ab + (long)(c * 16 + srl) * 512 + k0 + scl,
                      (char*)As[buf] + c * 1024);
            else
                g2l16(Bb + (long)((c - 8) * 16 + srl) * 512 + k0 + scl,
                      (char*)Bs[buf] + (c - 8) * 1024);
        }
    };
    stage(0);
    stage(1);
#define ER_STEP(T, W)                                           \
    W;                                                          \
    BARRIER_FENCE;                                              \
    if ((T) + 2 < 16) stage((T) + 2);                           \
    TILE_MFMA(As[(T) & 3], Bs[(T) & 3])
    ER_STEP(0, VMCNT4)  ER_STEP(1, VMCNT4)  ER_STEP(2, VMCNT4)
    ER_STEP(3, VMCNT4)  ER_STEP(4, VMCNT4)  ER_STEP(5, VMCNT4)
    ER_STEP(6, VMCNT4)  ER_STEP(7, VMCNT4)  ER_STEP(8, VMCNT4)
    ER_STEP(9, VMCNT4)  ER_STEP(10, VMCNT4) ER_STEP(11, VMCNT4)
    ER_STEP(12, VMCNT4) ER_STEP(13, VMCNT4) ER_STEP(14, VMCNT4)
    ER_STEP(15, VMCNT0)
#undef ER_STEP
    __syncthreads();   // all MFMA done; LDS buffers dead -> lt overlay safe
    int bb = m0 >> 11;                  // batch
    int tbase = m0 & (T_ - 1);
    #pragma unroll
    for (int r = 0; r < 4; ++r)
        #pragma unroll
        for (int c = 0; c < 4; ++c)
            #pragma unroll
            for (int e = 0; e < 4; ++e) {
                int rl = wm + r * 16 + q * 4 + e;        // t-local 0..127
                int col = n0 + wn + c * 16 + ln16;
                float v = fmaxf(acc[r][c][e], 0.f);
                xsp[(long)(m0 + rl) * HN_ + col] = f2b(v);
                int n = col & (NL_ - 1);
                int n2 = n >> 1;
                float fr = exp2f(-(float)n2 * 0.125f) *
                           (float)(1.0 / (2.0 * M_PI));
                float ph = (float)(tbase + rl) * fr;
                ph = (ph - floorf(ph)) * (float)(2.0 * M_PI);
                float s, cc;
                __sincosf(ph, &s, &cc);
                float vp = __shfl_xor(v, 1, 64);   // partner col^1
                float o = (n & 1) ? (v * cc + vp * s) : (v * cc - vp * s);
                int hh = col >> 8;
                qrh[((long)(bb * 8 + hh) * T_ + tbase + rl) * NL_ + n] = f2b(o);
                lt[wn + c * 16 + ln16][rl] = f2b(o);
            }
    __syncthreads();
    {
        int nrow = tid >> 1, tseg = (tid & 1) * 64;
        int colg = n0 + nrow;
        int hh = colg >> 8, nn = colg & (NL_ - 1);
        long ob = ((long)(bb * 8 + hh) * NL_ + nn) * T_ + tbase + tseg;
        #pragma unroll
        for (int u = 0; u < 16; ++u)
            *(us4*)&qrT[ob + u * 4] = *(const us4*)&lt[nrow][tseg + u * 4];
    }
}

// ---------------------------------------------------------------------------
// CT-GEMM (CHUNK=256), counted-vmcnt pipeline: Ct[z][j][d][n] = X_j^T @ QR_j.
// grid (16 z, 2 nt, 32 = j*4+mt).
__global__ __launch_bounds__(256) void ct_gemm(
    const unsigned short* __restrict__ xsT,   // [B][D][T]
    const unsigned short* __restrict__ qrT,   // [B*NH][NL][T]
    unsigned short* __restrict__ Ct) {        // [z*8+j][512][256]
    int z = blockIdx.x, nt = blockIdx.y;
    int j = blockIdx.z >> 2, mt = blockIdx.z & 3;
    int b = z >> 3;
    const unsigned short* Ab =
        xsT + (long)b * D_ * T_ + (long)(mt * 128) * T_ + j * 256;
    const unsigned short* Bb =
        qrT + (long)z * NL_ * T_ + (long)(nt * 128) * T_ + j * 256;
    __shared__ unsigned short As[3][128][32];
    __shared__ unsigned short Bs[3][128][32];
    TILE_IDS
    v4f acc[4][4] = {};
    auto stage = [&](int t, int buf) {
        int k0 = t * 32;
        #pragma unroll
        for (int ci = 0; ci < 4; ++ci) {
            int c = wid * 4 + ci;
            if (c < 8)
                g2l16(Ab + (long)(c * 16 + srl) * T_ + k0 + scl,
                      (char*)As[buf] + c * 1024);
            else
                g2l16(Bb + (long)((c - 8) * 16 + srl) * T_ + k0 + scl,
                      (char*)Bs[buf] + (c - 8) * 1024);
        }
    };
    stage(0, 0);
    stage(1, 1);
    int bcur = 0, bnxt = 2;
    for (int t = 0; t < 8; ++t) {
        if (t + 1 < 8) { VMCNT4; } else { VMCNT0; }
        BARRIER_FENCE;
        if (t + 2 < 8) stage(t + 2, bnxt);
        TILE_MFMA(As[bcur], Bs[bcur])
        bcur = bcur + 1 == 3 ? 0 : bcur + 1;
        bnxt = bnxt + 1 == 3 ? 0 : bnxt + 1;
    }
    unsigned short* ob = Ct + ((long)z * 8 + j) * 512 * 256;
    #pragma unroll
    for (int r = 0; r < 4; ++r)
        #pragma unroll
        for (int c = 0; c < 4; ++c)
            #pragma unroll
            for (int e = 0; e < 4; ++e) {
                int row = mt * 128 + wm + r * 16 + q * 4 + e;      // d
                int col = nt * 128 + wn + c * 16 + ln16;           // n
                ob[(long)row * 256 + col] = f2b(acc[r][c][e]);
            }
}

// ---------------------------------------------------------------------------
// PREFIX: in-place exclusive prefix over 8 chunks (slab loads prefetched).
__global__ __launch_bounds__(256) void prefix_k(unsigned short* __restrict__ Ct) {
    int z = blockIdx.x, dg = blockIdx.y;
    int d = dg * 8 + (threadIdx.x >> 5);
    int n0 = (threadIdx.x & 31) * 8;
    long base = ((long)z * 8) * 512 * 256 + (long)d * 256 + n0;
    constexpr long S = 512 * 256;
    us8 vals[8];
    #pragma unroll
    for (int i = 0; i < 8; ++i)
        vals[i] = *(const us8*)&Ct[base + (long)i * S];
    float acc[8] = {};
    #pragma unroll
    for (int i = 0; i < 8; ++i) {
        us8 o;
        #pragma unroll
        for (int e = 0; e < 8; ++e) o[e] = f2b(acc[e]);
        *(us8*)&Ct[base + (long)i * S] = o;
        #pragma unroll
        for (int e = 0; e < 8; ++e) acc[e] += b2f(vals[i][e]);
    }
}

// ---------------------------------------------------------------------------
// SDIAG (CHUNK=256), counted-vmcnt pipeline: 3 quadrants of strict_tril
// (QR_i @ QR_i^T).  qq=0 -> (0,0) masked, qq=1 -> (1,0) dense, qq=2 -> (1,1)
// masked.  grid (16 z, 8 i, 3 qq).
__global__ __launch_bounds__(256) void sdiag(const unsigned short* __restrict__ qr,
                                             unsigned short* __restrict__ Sd) {
    int z = blockIdx.x, i = blockIdx.y, qq = blockIdx.z;
    int qm = (qq + 1) >> 1, qn = qq >> 1;         // (0,0),(1,0),(1,1)
    const unsigned short* Ab =
        qr + ((long)z * T_ + i * 256 + qm * 128) * NL_;
    const unsigned short* Bb =
        qr + ((long)z * T_ + i * 256 + qn * 128) * NL_;
    bool dual = (qm != qn);
    __shared__ unsigned short As[3][128][32];
    __shared__ unsigned short Bs[3][128][32];
    TILE_IDS
    v4f acc[4][4] = {};
    auto stage = [&](int t, int buf) {
        int k0 = t * 32;
        #pragma unroll
        for (int ci = 0; ci < 2; ++ci) {
            int c = wid * 2 + ci;
            g2l16(Ab + (long)(c * 16 + srl) * NL_ + k0 + scl,
                  (char*)As[buf] + c * 1024);
            if (dual)
                g2l16(Bb + (long)(c * 16 + srl) * NL_ + k0 + scl,
                      (char*)Bs[buf] + c * 1024);
        }
    };
    stage(0, 0);
    stage(1, 1);
    int bcur = 0, bnxt = 2;
    for (int t = 0; t < 8; ++t) {
        if (t + 1 < 8) { if (dual) { VMCNT4; } else { VMCNT2; } }
        else           { VMCNT0; }
        BARRIER_FENCE;
        if (t + 2 < 8) stage(t + 2, bnxt);
        if (dual) { TILE_MFMA(As[bcur], Bs[bcur]) }
        else      { TILE_MFMA(As[bcur], As[bcur]) }
        bcur = bcur + 1 == 3 ? 0 : bcur + 1;
        bnxt = bnxt + 1 == 3 ? 0 : bnxt + 1;
    }
    unsigned short* ob = Sd + ((long)z * 8 + i) * 65536;
    #pragma unroll
    for (int r = 0; r < 4; ++r)
        #pragma unroll
        for (int c = 0; c < 4; ++c)
            #pragma unroll
            for (int e = 0; e < 4; ++e) {
                int row = wm + r * 16 + q * 4 + e;
                int col = wn + c * 16 + ln16;
                float v = acc[r][c][e];
                if (!dual && row <= col) v = 0.f;   // strict causal (diag quad)
                ob[(qm * 128 + row) * 256 + qn * 128 + col] = f2b(v);
            }
}

// ---------------------------------------------------------------------------
// PXG (CHUNK=256), counted-vmcnt pipeline: unnormalized yKV =
// QR_i @ P_{chunk(i)} + Sd-halfstrip @ X.  Seg2 K = 128 or 256 by half.
// Emits exact fp32 per-row (sum, sumsq) partials.  grid (16 z, 16 i, 4 nt).
__global__ __launch_bounds__(256) void pxg(
    const unsigned short* __restrict__ qr,    // [z][T][NL]
    const unsigned short* __restrict__ Pt,    // [z*8+j][512][256] (prefix)
    const unsigned short* __restrict__ Sd,    // [z*8+j][256][256]
    const unsigned short* __restrict__ xsT,   // [B][D][T]
    unsigned short* __restrict__ ykvu,        // [NH][BT][D] (unnormalized)
    float* __restrict__ part) {               // [z*16+i][4][128][2]
    int z = blockIdx.x, i = blockIdx.y, nt = blockIdx.z;
    int b = z >> 3, h = z & 7;
    int n0 = nt * 128;
    int i256 = i >> 1, hf2 = i & 1;
    const unsigned short* A1 = qr + ((long)z * T_ + i * 128) * NL_;
    const unsigned short* B1 =
        Pt + ((long)z * 8 + i256) * 512 * 256 + (long)n0 * 256;
    const unsigned short* A2 = Sd + ((long)z * 8 + i256) * 65536 +
                               (long)hf2 * 128 * 256;
    const unsigned short* B2 =
        xsT + (long)b * D_ * T_ + (long)n0 * T_ + i256 * 256;
    __shared__ unsigned short As[3][128][32];   // 24 KB
    __shared__ unsigned short Bs[3][128][32];   // 24 KB
    __shared__ float sred[128][2][2];           //  2 KB
    TILE_IDS
    v4f acc[4][4] = {};
    int NS = 12 + hf2 * 4;   // 8 seg1 steps + 4 or 8 seg2 steps
    auto stage = [&](int s, int buf) {
        const unsigned short* Ap;
        const unsigned short* Bp;
        long lda, ldb;
        int k0;
        if (s < 8) { Ap = A1; lda = NL_; Bp = B1; ldb = 256; k0 = s * 32; }
        else       { Ap = A2; lda = 256; Bp = B2; ldb = T_;  k0 = (s - 8) * 32; }
        #pragma unroll
        for (int ci = 0; ci < 4; ++ci) {
            int c = wid * 4 + ci;
            if (c < 8)
                g2l16(Ap + (long)(c * 16 + srl) * lda + k0 + scl,
                      (char*)As[buf] + c * 1024);
            else
                g2l16(Bp + (long)((c - 8) * 16 + srl) * ldb + k0 + scl,
                      (char*)Bs[buf] + (c - 8) * 1024);
        }
    };
    stage(0, 0);
    stage(1, 1);
    int bcur = 0, bnxt = 2;
    for (int s = 0; s < NS; ++s) {
        if (s + 1 < NS) { VMCNT4; } else { VMCNT0; }
        BARRIER_FENCE;
        if (s + 2 < NS) stage(s + 2, bnxt);
        TILE_MFMA(As[bcur], Bs[bcur])
        bcur = bcur + 1 == 3 ? 0 : bcur + 1;
        bnxt = bnxt + 1 == 3 ? 0 : bnxt + 1;
    }
    // ---- bf16 store + exact row partial sums (fp32 from accumulators) ----
    long obase = ((long)h * BT_ + (long)b * T_ + i * 128) * D_ + n0;
    #pragma unroll
    for (int r = 0; r < 4; ++r) {
        float s1[4] = {}, s2[4] = {};
        #pragma unroll
        for (int c = 0; c < 4; ++c)
            #pragma unroll
            for (int e = 0; e < 4; ++e) {
                float v = acc[r][c][e];
                s1[e] += v;
                s2[e] += v * v;
                int rl = wm + r * 16 + q * 4 + e;
                int col = wn + c * 16 + ln16;
                ykvu[obase + (long)rl * D_ + col] = f2b(v);
            }
        #pragma unroll
        for (int e = 0; e < 4; ++e) {
            #pragma unroll
            for (int off = 1; off < 16; off <<= 1) {
                s1[e] += __shfl_xor(s1[e], off, 64);
                s2[e] += __shfl_xor(s2[e], off, 64);
            }
            if (ln16 == 0) {
                int rl = wm + r * 16 + q * 4 + e;
                sred[rl][wid >> 1][0] = s1[e];
                sred[rl][wid >> 1][1] = s2[e];
            }
        }
    }
    __syncthreads();
    if (tid < 128) {
        float a = sred[tid][0][0] + sred[tid][1][0];
        float sq = sred[tid][0][1] + sred[tid][1][1];
        long pb = ((((long)z * 16 + i) * 4 + nt) * 128 + tid) * 2;
        part[pb] = a;
        part[pb + 1] = sq;
    }
}

// ---------------------------------------------------------------------------
// LNSTATS: fold pxg's 4 nt-quadrant partials into per-row (mu, inv).
__global__ __launch_bounds__(128) void lnstats(const float* __restrict__ part,
                                               float* __restrict__ muinv) {
    int z = blockIdx.x, i = blockIdx.y, t = threadIdx.x;
    long pb = ((((long)z * 16 + i) * 4) * 128 + t) * 2;
    float s1 = part[pb] + part[pb + 256] + part[pb + 512] + part[pb + 768];
    float s2 = part[pb + 1] + part[pb + 257] + part[pb + 513] + part[pb + 769];
    float mu = s1 * (1.0f / 512.0f);
    float var = s2 * (1.0f / 512.0f) - mu * mu;
    float inv = rsqrtf(var + 1e-5f);
    int b = z >> 3, h = z & 7;
    long row = (long)h * BT_ + (long)b * T_ + i * 128 + t;
    muinv[row * 2]     = mu;
    muinv[row * 2 + 1] = inv;
}

// ---------------------------------------------------------------------------
// COLSUM: colsum[g] = sum_d encvT[g][d] (fp32), g in [0, HN).  One wave/row.
__global__ __launch_bounds__(256) void colsum_k(
    const unsigned short* __restrict__ encvT, float* __restrict__ cs) {
    int lane = threadIdx.x & 63, wv = threadIdx.x >> 6;
    int g = blockIdx.x * 4 + wv;
    us8 v = *(const us8*)&encvT[(long)g * 512 + lane * 8];
    float s = 0.f;
    #pragma unroll
    for (int e = 0; e < 8; ++e) s += b2f(v[e]);
    #pragma unroll
    for (int off = 1; off < 64; off <<= 1) s += __shfl_xor(s, off, 64);
    if (lane == 0) cs[g] = s;
}

// ---------------------------------------------------------------------------
// Transpose + cast fp32 -> bf16: out[Cc][R] = (bf16) in[R][Cc], batched.
__global__ __launch_bounds__(256) void trans_cast(
    const float* __restrict__ in, long sIn, unsigned short* __restrict__ out,
    long sOut, int R, int Cc) {
    __shared__ float tl[32][33];
    int z = blockIdx.z;
    int r0 = blockIdx.y * 32, c0 = blockIdx.x * 32;
    int tx = threadIdx.x & 31, ty = threadIdx.x >> 5;
    const float* ip = in + (long)z * sIn;
    unsigned short* op = out + (long)z * sOut;
    #pragma unroll
    for (int j = 0; j < 4; ++j)
        tl[ty + j * 8][tx] = ip[(long)(r0 + ty + j * 8) * Cc + c0 + tx];
    __syncthreads();
    #pragma unroll
    for (int j = 0; j < 4; ++j)
        op[(long)(c0 + ty + j * 8) * R + r0 + tx] = f2b(tl[tx][ty + j * 8]);
}

// bf16 transpose (no cast): out[Cc][R] = in[R][Cc], batched.  Bitwise
// identical to trans_cast when in == f2b(source) elementwise.
__global__ __launch_bounds__(256) void trans16(
    const unsigned short* __restrict__ in, long sIn,
    unsigned short* __restrict__ out, long sOut, int R, int Cc) {
    __shared__ unsigned short tl[32][34];
    int z = blockIdx.z;
    int r0 = blockIdx.y * 32, c0 = blockIdx.x * 32;
    int tx = threadIdx.x & 31, ty = threadIdx.x >> 5;
    const unsigned short* ip = in + (long)z * sIn;
    unsigned short* op = out + (long)z * sOut;
    #pragma unroll
    for (int j = 0; j < 4; ++j)
        tl[ty + j * 8][tx] = ip[(long)(r0 + ty + j * 8) * Cc + c0 + tx];
    __syncthreads();
    #pragma unroll
    for (int j = 0; j < 4; ++j)
        op[(long)(c0 + ty + j * 8) * R + r0 + tx] = tl[tx][ty + j * 8];
}

// fp32 -> bf16 elementwise (n multiple of 1024)
__global__ __launch_bounds__(256) void cast_b(const float* __restrict__ in,
                                              unsigned short* __restrict__ out) {
    long i = ((long)blockIdx.x * 256 + threadIdx.x) * 4;
    float4 v = *(const float4*)&in[i];
    ushort4 o;
    o.x = f2b(v.x); o.y = f2b(v.y); o.z = f2b(v.z); o.w = f2b(v.w);
    *(ushort4*)&out[i] = o;
}

// out = t0+t1+t2+t3 + bias (4 split-K slices, rows of 512)
__global__ __launch_bounds__(256) void add_out4(const float* __restrict__ t,
                                                long slice,
                                                const float* __restrict__ bias,
                                                float* __restrict__ o) {
    long i = ((long)blockIdx.x * 256 + threadIdx.x) * 4;
    float4 v0 = *(const float4*)&t[i];
    float4 v1 = *(const float4*)&t[i + slice];
    float4 v2 = *(const float4*)&t[i + 2 * slice];
    float4 v3 = *(const float4*)&t[i + 3 * slice];
    float4 bv = *(const float4*)&bias[i & 511];
    float4 r;
    r.x = v0.x + v1.x + v2.x + v3.x + bv.x;
    r.y = v0.y + v1.y + v2.y + v3.y + bv.y;
    r.z = v0.z + v1.z + v2.z + v3.z + bv.z;
    r.w = v0.w + v1.w + v2.w + v3.w + bv.w;
    *(float4*)&o[i] = r;
}

// ---------------------------------------------------------------------------
// LayerNorm helpers (rows of 512, 256 threads, float2 per thread)
__device__ inline float2 block_reduce2(float a, float b) {
    __shared__ float sa[4], sb[4];
    #pragma unroll
    for (int off = 32; off; off >>= 1) {
        a += __shfl_down(a, off, 64);
        b += __shfl_down(b, off, 64);
    }
    __syncthreads();
    int w = threadIdx.x >> 6;
    if ((threadIdx.x & 63) == 0) { sa[w] = a; sb[w] = b; }
    __syncthreads();
    return make_float2(sa[0] + sa[1] + sa[2] + sa[3],
                       sb[0] + sb[1] + sb[2] + sb[3]);
}
__device__ inline float2 ln_pair(float2 v) {
    float2 s = block_reduce2(v.x + v.y, 0.f);
    float mu = s.x * (1.0f / 512.0f);
    float dx = v.x - mu, dy = v.y - mu;
    float2 q = block_reduce2(dx * dx + dy * dy, 0.f);
    float inv = rsqrtf(q.x * (1.0f / 512.0f) + 1e-5f);
    return make_float2(dx * inv, dy * inv);
}

// LN(sum of 4 slices + bias) -> fp32 + bf16
__global__ __launch_bounds__(256) void ln_dual4(const float* __restrict__ t,
                                                long slice,
                                                const float* __restrict__ bias,
                                                float* __restrict__ outf,
                                                unsigned short* __restrict__ outb) {
    long row = blockIdx.x;
    int c = threadIdx.x * 2;
    long i = row * 512 + c;
    float2 v0 = *(const float2*)&t[i];
    float2 v1 = *(const float2*)&t[i + slice];
    float2 v2 = *(const float2*)&t[i + 2 * slice];
    float2 v3 = *(const float2*)&t[i + 3 * slice];
    float2 bv = *(const float2*)&bias[c];
    float2 v = make_float2(v0.x + v1.x + v2.x + v3.x + bv.x,
                           v0.y + v1.y + v2.y + v3.y + bv.y);
    float2 o = ln_pair(v);
    *(float2*)&outf[i] = o;
    ushort2 ob; ob.x = f2b(o.x); ob.y = f2b(o.y);
    *(ushort2*)&outb[i] = ob;
}

// xs_next = LN(x_res + LN(sum of 4 ymlp slices)) -> fp32 + bf16
__global__ __launch_bounds__(256) void combine_dual4(
    const float* __restrict__ t, long slice, const float* __restrict__ xres,
    float* __restrict__ outf, unsigned short* __restrict__ outb) {
    long row = blockIdx.x;
    int c = threadIdx.x * 2;
    long i = row * 512 + c;
    float2 v0 = *(const float2*)&t[i];
    float2 v1 = *(const float2*)&t[i + slice];
    float2 v2 = *(const float2*)&t[i + 2 * slice];
    float2 v3 = *(const float2*)&t[i + 3 * slice];
    float2 y = make_float2(v0.x + v1.x + v2.x + v3.x,
                           v0.y + v1.y + v2.y + v3.y);
    float2 l = ln_pair(y);
    float2 r = *(const float2*)&xres[i];
    float2 z = make_float2(r.x + l.x, r.y + l.y);
    float2 o = ln_pair(z);
    *(float2*)&outf[i] = o;
    ushort2 ob; ob.x = f2b(o.x); ob.y = f2b(o.y);
    *(ushort2*)&outb[i] = ob;
}

// ---------------------------------------------------------------------------
extern "C" void kernel_launch(void* const* d_in, const int* in_sizes, int n_in,
                              void* d_out, int out_size, void* d_ws,
                              size_t ws_size, hipStream_t stream) {
    const float* x      = (const float*)d_in[0];
    const float* w_in   = (const float*)d_in[1];
    const float* b_in   = (const float*)d_in[2];
    const float* enc    = (const float*)d_in[3];
    const float* enc_v  = (const float*)d_in[4];
    const float* dec    = (const float*)d_in[5];
    const float* head_w = (const float*)d_in[6];
    const float* head_b = (const float*)d_in[7];
    float* out = (float*)d_out;

    // ---- workspace (~170 MB) ----
    char* w = (char*)d_ws;
    auto alloc = [&](size_t bytes) { void* p = (void*)w; w += bytes; return p; };
    unsigned short* w_inT = (unsigned short*)alloc((size_t)512 * 512 * 2);
    unsigned short* headT = (unsigned short*)alloc((size_t)512 * 512 * 2);
    unsigned short* encT  = (unsigned short*)alloc((size_t)NH_ * NL_ * D_ * 2);
    unsigned short* encvT = (unsigned short*)alloc((size_t)NH_ * NL_ * D_ * 2);
    unsigned short* decT  = (unsigned short*)alloc((size_t)D_ * HN_ * 2);
    unsigned short* xb    = (unsigned short*)alloc((size_t)BT_ * D_ * 2);
    float*          tmp   = (float*)alloc((size_t)4 * BT_ * D_ * 4);  // 4 K-slices
    float*          xsf0  = (float*)alloc((size_t)BT_ * D_ * 4);
    float*          xsf1  = (float*)alloc((size_t)BT_ * D_ * 4);
    unsigned short* xs_b  = (unsigned short*)alloc((size_t)BT_ * D_ * 2);
    unsigned short* xsT   = (unsigned short*)alloc((size_t)B_ * D_ * T_ * 2);
    unsigned short* xsp   = (unsigned short*)alloc((size_t)BT_ * HN_ * 2);
    unsigned short* qrh   = (unsigned short*)alloc((size_t)BT_ * HN_ * 2);
    unsigned short* qrT   = (unsigned short*)alloc((size_t)BT_ * HN_ * 2);
    unsigned short* Ct    = (unsigned short*)alloc((size_t)128 * 512 * 256 * 2); // 33.5 MB
    unsigned short* Sd    = (unsigned short*)alloc((size_t)128 * 256 * 256 * 2); // 16.8 MB
    unsigned short* ykv   = (unsigned short*)alloc((size_t)NH_ * BT_ * D_ * 2);
    float*          part  = (float*)alloc((size_t)256 * 4 * 128 * 2 * 4);        //  1 MB
    float*          muinv = (float*)alloc((size_t)NH_ * BT_ * 2 * 4);            // 256 KB
    float*          csum  = (float*)alloc((size_t)HN_ * 4);                      //   8 KB
    const long SL = (long)BT_ * D_;   // split-K slice stride (elements)

    // ---- prep ----
    cast_b<<<BT_ * D_ / 1024, 256, 0, stream>>>(x, xb);
    trans_cast<<<dim3(16, 16, 1), 256, 0, stream>>>(w_in, 0, w_inT, 0, 512, 512);
    trans_cast<<<dim3(16, 16, 1), 256, 0, stream>>>(head_w, 0, headT, 0, 512, 512);
    trans_cast<<<dim3(8, 16, 8), 256, 0, stream>>>(enc, (long)D_ * NL_, encT,
                                                   (long)NL_ * D_, D_, NL_);
    trans_cast<<<dim3(8, 16, 8), 256, 0, stream>>>(enc_v, (long)D_ * NL_, encvT,
                                                   (long)NL_ * D_, D_, NL_);
    trans_cast<<<dim3(16, 64, 1), 256, 0, stream>>>(dec, 0, decT, 0, HN_, D_);
    colsum_k<<<HN_ / 4, 256, 0, stream>>>(encvT, csum);

    // ---- xs = LN(x @ w_in + b_in)  (split-K=4) ----
    gemm128<false, false, false, false>
        <<<dim3(4, 32, 4), 256, 0, stream>>>(xb, D_, 128, w_inT, D_, 128, tmp,
                                             D_, SL, nullptr, 128, nullptr,
                                             nullptr);
    ln_dual4<<<BT_, 256, 0, stream>>>(tmp, SL, b_in, xsf0, xs_b);
    trans16<<<dim3(16, 64, 2), 256, 0, stream>>>(xs_b, (long)T_ * D_, xsT,
                                                 (long)D_ * T_, T_, D_);

    float* xin = xsf0;
    float* xout = xsf1;
    for (int l = 0; l < 3; ++l) {
        // x_sparse + rope + both QR layouts, one kernel (counted-vmcnt pipe)
        enc_rope<<<dim3(16, 32), 256, 0, stream>>>(xs_b, encT, xsp, qrh, qrT);
        // linear-attention state tiles (chunk 256): Ct[z][j] = X_j^T @ QR_j
        ct_gemm<<<dim3(16, 2, 32), 256, 0, stream>>>(xsT, qrT, Ct);
        // exclusive prefix over 8 chunks (in place)
        prefix_k<<<dim3(16, 64), 256, 0, stream>>>(Ct);
        // diagonal strict 256x256 scores (3 quadrants)
        sdiag<<<dim3(16, 8, 3), 256, 0, stream>>>(qrh, Sd);
        // yKV(unnorm) = QR_i @ P + Sd-half @ X  + row stats
        pxg<<<dim3(16, 16, 4), 256, 0, stream>>>(qrh, Ct, Sd, xsT, ykv, part);
        // fold partials -> per-row (mu, inv)
        lnstats<<<dim3(16, 16), 128, 0, stream>>>(part, muinv);
        // xy = relu(LN(yKV)[h] @ enc_v[h]) * x_sparse, LN folded via linearity
        gemm128<true, true, true, true>
            <<<dim3(2, 32, 8), 256, 0, stream>>>(
                ykv, D_, (long)BT_ * D_, encvT, D_, (long)NL_ * D_, xsp, HN_,
                NL_, xsp, 512, muinv, csum);
        // yMLP = xy @ decoder  (split-K=4) -> fp32 slices
        gemm128<false, false, false, false>
            <<<dim3(4, 32, 4), 256, 0, stream>>>(
                xsp, HN_, 512, decT, HN_, 512, tmp, D_, SL, nullptr, 512,
                nullptr, nullptr);
        // xs = LN(x_res + LN(yMLP))
        combine_dual4<<<BT_, 256, 0, stream>>>(tmp, SL, xin, xout, xs_b);
        trans16<<<dim3(16, 64, 2), 256, 0, stream>>>(xs_b, (long)T_ * D_, xsT,
                                                     (long)D_ * T_, T_, D_);
        float* t = xin; xin = xout; xout = t;
    }

    // logits = xs @ head_w + head_b  (split-K=4)
    gemm128<false, false, false, false>
        <<<dim3(4, 32, 4), 256, 0, stream>>>(xs_b, D_, 128, headT, D_, 128, tmp,
                                             D_, SL, nullptr, 128, nullptr,
                                             nullptr);
    add_out4<<<BT_ * 512 / 1024, 256, 0, stream>>>(tmp, SL, head_b, out);
}

// Round 17
// 597.528 us; speedup vs baseline: 1.0800x; 1.0800x over previous
//
#include <hip/hip_runtime.h>
#include <math.h>

constexpr int B_  = 2;
constexpr int T_  = 2048;
constexpr int D_  = 512;
constexpr int NH_ = 8;
constexpr int NL_ = 256;
constexpr int HN_ = NH_ * NL_;   // 2048
constexpr int BT_ = B_ * T_;     // 4096

typedef __bf16 v8bf __attribute__((ext_vector_type(8)));
typedef float  v4f  __attribute__((ext_vector_type(4)));
typedef unsigned short us8 __attribute__((ext_vector_type(8)));
typedef unsigned short us4 __attribute__((ext_vector_type(4)));

__device__ inline unsigned short f2b(float f) {
    union { float f; unsigned u; } v{f};
    unsigned r = v.u + 0x7FFF + ((v.u >> 16) & 1);   // rtne
    return (unsigned short)(r >> 16);
}
__device__ inline float b2f(unsigned short u) {
    union { unsigned u; float f; } v{(unsigned)u << 16};
    return v.f;
}

// async 16B global->LDS (per-lane gaddr; LDS dest = wave-uniform base + lane*16)
__device__ __forceinline__ void g2l16(const void* g, void* l) {
    __builtin_amdgcn_global_load_lds(
        (const __attribute__((address_space(1))) void*)g,
        (__attribute__((address_space(3))) void*)l, 16, 0, 0);
}

// counted waits (T4)
#define VMCNT4 asm volatile("s_waitcnt vmcnt(4)" ::: "memory")
#define VMCNT0 asm volatile("s_waitcnt vmcnt(0)" ::: "memory")
#define BARRIER_FENCE                                   \
    __builtin_amdgcn_s_barrier();                       \
    asm volatile("" ::: "memory")

// ===========================================================================
// Shared lane decomposition.
#define TILE_IDS                                              \
    int tid = threadIdx.x;                                    \
    int lane = tid & 63, wid = tid >> 6;                      \
    int wm = (wid & 1) * 64, wn = (wid >> 1) * 64;            \
    int ln16 = lane & 15, q = lane >> 4;                      \
    int srl = lane >> 2, scl = (lane & 3) * 8;                \
    (void)wm; (void)wn;

// 128x128 tile staging (32-wide K slice): 16 chunks of 16 rows x 32 cols.
#define T128_STAGE(Ab, lda, Bb, ldb, k0, buf)                 \
    _Pragma("unroll")                                         \
    for (int ci = 0; ci < 4; ++ci) {                          \
        int c = wid * 4 + ci;                                 \
        if (c < 8) {                                          \
            int r = c * 16 + srl;                             \
            g2l16(Ab + (long)r * lda + (k0) + scl,            \
                  (char*)As[buf] + c * 1024);                 \
        } else {                                              \
            int r = (c - 8) * 16 + srl;                       \
            g2l16(Bb + (long)r * ldb + (k0) + scl,            \
                  (char*)Bs[buf] + (c - 8) * 1024);           \
        }                                                     \
    }

// 128x128 MFMA step: 4x4 16x16x32 per wave (16 MFMA).
#define TILE_MFMA(Asx, Bsx)                                   \
    {                                                         \
        v8bf af[4], bfr[4];                                   \
        _Pragma("unroll")                                     \
        for (int r = 0; r < 4; ++r)                           \
            af[r] = *(const v8bf*)&Asx[wm + r * 16 + ln16][q * 8]; \
        _Pragma("unroll")                                     \
        for (int c = 0; c < 4; ++c)                           \
            bfr[c] = *(const v8bf*)&Bsx[wn + c * 16 + ln16][q * 8]; \
        _Pragma("unroll")                                     \
        for (int r = 0; r < 4; ++r)                           \
            _Pragma("unroll")                                 \
            for (int c = 0; c < 4; ++c)                       \
                acc[r][c] = __builtin_amdgcn_mfma_f32_16x16x32_bf16( \
                    af[r], bfr[c], acc[r][c], 0, 0, 0);       \
    }

// ---------------------------------------------------------------------------
// Generic 128x128-tile bf16 GEMM: C[M,N] = A[M,K] @ Bt[N,K]^T, z-batched.
// KS = K-step per barrier (32 or 64).  [r16 lesson: keep KS=64 2-phase —
// converting to BK=32 counted-vmcnt halved MFMA/barrier and regressed +64us.]
// LNA: LN(A)@B = inv * (A@B - mu * colsum(B)) in the epilogue.
template <int KS, bool RELU, bool MUL, bool BF16OUT, bool LNA>
__global__ __launch_bounds__(256) void gemm128(
    const unsigned short* __restrict__ A, int lda, long sA,
    const unsigned short* __restrict__ Bt, int ldb, long sB,
    void* __restrict__ Cv, int ldc, long sC,
    const unsigned short* __restrict__ mulp, int K,
    const float* __restrict__ muinv, const float* __restrict__ colsum) {
    constexpr int NHF = KS / 32;
    int m0 = blockIdx.y * 128, n0 = blockIdx.x * 128, z = blockIdx.z;
    __shared__ unsigned short As[2][NHF][128][32];
    __shared__ unsigned short Bs[2][NHF][128][32];
    const unsigned short* Ab = A  + (long)z * sA + (long)m0 * lda;
    const unsigned short* Bb = Bt + (long)z * sB + (long)n0 * ldb;
    TILE_IDS
    v4f acc[4][4] = {};
    auto stageK = [&](int k0, int buf) {
        #pragma unroll
        for (int h = 0; h < NHF; ++h)
            #pragma unroll
            for (int ci = 0; ci < 4; ++ci) {
                int c = wid * 4 + ci;
                if (c < 8)
                    g2l16(Ab + (long)(c * 16 + srl) * lda + k0 + h * 32 + scl,
                          (char*)As[buf][h] + c * 1024);
                else
                    g2l16(Bb + (long)((c - 8) * 16 + srl) * ldb + k0 + h * 32 +
                              scl,
                          (char*)Bs[buf][h] + (c - 8) * 1024);
            }
    };
    stageK(0, 0);
    __syncthreads();
    int cur = 0;
    for (int k0 = 0; k0 < K; k0 += KS) {
        if (k0 + KS < K) stageK(k0 + KS, cur ^ 1);
        #pragma unroll
        for (int h = 0; h < NHF; ++h)
            TILE_MFMA(As[cur][h], Bs[cur][h])
        __syncthreads();
        cur ^= 1;
    }
    float* Cf = (float*)Cv;
    unsigned short* Cb = (unsigned short*)Cv;
    long zoff = (long)z * sC;
    #pragma unroll
    for (int r = 0; r < 4; ++r)
        #pragma unroll
        for (int c = 0; c < 4; ++c)
            #pragma unroll
            for (int e = 0; e < 4; ++e) {
                int row = m0 + wm + r * 16 + q * 4 + e;
                int col = n0 + wn + c * 16 + ln16;
                float v = acc[r][c][e];
                if (LNA) {
                    float2 mi = *(const float2*)&muinv[((long)z * BT_ + row) * 2];
                    float cs = colsum[(long)z * NL_ + col];
                    v = mi.y * (v - mi.x * cs);
                }
                if (RELU) v = fmaxf(v, 0.f);
                long idx = zoff + (long)row * ldc + col;
                if (MUL) v *= b2f(mulp[idx]);
                if (BF16OUT) Cb[idx] = f2b(v);
                else         Cf[idx] = v;
            }
}

// ---------------------------------------------------------------------------
// ENC+ROPE fused, 128x128 tile, counted-vmcnt pipeline (measured r15):
// BK=32, 4 LDS buffers (64 KB), depth-2 prefetch.  grid (16 nt, 32 mt).
// [r13 lesson: 128x64 tiles regressed — bandwidth/structure-bound.]
__global__ __launch_bounds__(256) void enc_rope(
    const unsigned short* __restrict__ A,    // xs_b [BT][512]
    const unsigned short* __restrict__ Bt,   // encT [HN][512] K-major
    unsigned short* __restrict__ xsp,        // [BT][HN]
    unsigned short* __restrict__ qrh,        // [z][T][NL]
    unsigned short* __restrict__ qrT) {      // [z][NL][T]
    int m0 = blockIdx.y * 128, n0 = blockIdx.x * 128;
    __shared__ unsigned short As[4][128][32];   // 32 KB (4 bufs x 8 KB)
    __shared__ unsigned short Bs[4][128][32];   // 32 KB
    unsigned short (*lt)[136] = (unsigned short(*)[136])&As[0][0][0]; // 34.8 KB
    const unsigned short* Ab = A + (long)m0 * 512;
    const unsigned short* Bb = Bt + (long)n0 * 512;
    TILE_IDS
    v4f acc[4][4] = {};
    auto stage = [&](int t) {
        int k0 = t * 32, buf = t & 3;
        #pragma unroll
        for (int ci = 0; ci < 4; ++ci) {
            int c = wid * 4 + ci;
            if (c < 8)
                g2l16(Ab + (long)(c * 16 + srl) * 512 + k0 + scl,
                      (char*)As[buf] + c * 1024);
            else
                g2l16(Bb + (long)((c - 8) * 16 + srl) * 512 + k0 + scl,
                      (char*)Bs[buf] + (c - 8) * 1024);
        }
    };
    stage(0);
    stage(1);
#define ER_STEP(T, W)                                           \
    W;                                                          \
    BARRIER_FENCE;                                              \
    if ((T) + 2 < 16) stage((T) + 2);                           \
    TILE_MFMA(As[(T) & 3], Bs[(T) & 3])
    ER_STEP(0, VMCNT4)  ER_STEP(1, VMCNT4)  ER_STEP(2, VMCNT4)
    ER_STEP(3, VMCNT4)  ER_STEP(4, VMCNT4)  ER_STEP(5, VMCNT4)
    ER_STEP(6, VMCNT4)  ER_STEP(7, VMCNT4)  ER_STEP(8, VMCNT4)
    ER_STEP(9, VMCNT4)  ER_STEP(10, VMCNT4) ER_STEP(11, VMCNT4)
    ER_STEP(12, VMCNT4) ER_STEP(13, VMCNT4) ER_STEP(14, VMCNT4)
    ER_STEP(15, VMCNT0)
#undef ER_STEP
    __syncthreads();   // all MFMA done; LDS buffers dead -> lt overlay safe
    int bb = m0 >> 11;                  // batch
    int tbase = m0 & (T_ - 1);
    #pragma unroll
    for (int r = 0; r < 4; ++r)
        #pragma unroll
        for (int c = 0; c < 4; ++c)
            #pragma unroll
            for (int e = 0; e < 4; ++e) {
                int rl = wm + r * 16 + q * 4 + e;        // t-local 0..127
                int col = n0 + wn + c * 16 + ln16;
                float v = fmaxf(acc[r][c][e], 0.f);
                xsp[(long)(m0 + rl) * HN_ + col] = f2b(v);
                int n = col & (NL_ - 1);
                int n2 = n >> 1;
                float fr = exp2f(-(float)n2 * 0.125f) *
                           (float)(1.0 / (2.0 * M_PI));
                float ph = (float)(tbase + rl) * fr;
                ph = (ph - floorf(ph)) * (float)(2.0 * M_PI);
                float s, cc;
                __sincosf(ph, &s, &cc);
                float vp = __shfl_xor(v, 1, 64);   // partner col^1
                float o = (n & 1) ? (v * cc + vp * s) : (v * cc - vp * s);
                int hh = col >> 8;
                qrh[((long)(bb * 8 + hh) * T_ + tbase + rl) * NL_ + n] = f2b(o);
                lt[wn + c * 16 + ln16][rl] = f2b(o);
            }
    __syncthreads();
    {
        int nrow = tid >> 1, tseg = (tid & 1) * 64;
        int colg = n0 + nrow;
        int hh = colg >> 8, nn = colg & (NL_ - 1);
        long ob = ((long)(bb * 8 + hh) * NL_ + nn) * T_ + tbase + tseg;
        #pragma unroll
        for (int u = 0; u < 16; ++u)
            *(us4*)&qrT[ob + u * 4] = *(const us4*)&lt[nrow][tseg + u * 4];
    }
}

// ---------------------------------------------------------------------------
// CT-GEMM (CHUNK=256), 2-phase BK=32: Ct[z][j][d][n] = X_j^T @ QR_j.
// grid (16 z, 2 nt, 32 = j*4+mt).
__global__ __launch_bounds__(256) void ct_gemm(
    const unsigned short* __restrict__ xsT,   // [B][D][T]
    const unsigned short* __restrict__ qrT,   // [B*NH][NL][T]
    unsigned short* __restrict__ Ct) {        // [z*8+j][512][256]
    int z = blockIdx.x, nt = blockIdx.y;
    int j = blockIdx.z >> 2, mt = blockIdx.z & 3;
    int b = z >> 3;
    const unsigned short* Ab =
        xsT + (long)b * D_ * T_ + (long)(mt * 128) * T_ + j * 256;
    const unsigned short* Bb =
        qrT + (long)z * NL_ * T_ + (long)(nt * 128) * T_ + j * 256;
    __shared__ unsigned short As[2][128][32];
    __shared__ unsigned short Bs[2][128][32];
    TILE_IDS
    v4f acc[4][4] = {};
    T128_STAGE(Ab, T_, Bb, T_, 0, 0)
    __syncthreads();
    int cur = 0;
    for (int k0 = 0; k0 < 256; k0 += 32) {
        if (k0 + 32 < 256) { T128_STAGE(Ab, T_, Bb, T_, k0 + 32, cur ^ 1) }
        TILE_MFMA(As[cur], Bs[cur])
        __syncthreads();
        cur ^= 1;
    }
    unsigned short* ob = Ct + ((long)z * 8 + j) * 512 * 256;
    #pragma unroll
    for (int r = 0; r < 4; ++r)
        #pragma unroll
        for (int c = 0; c < 4; ++c)
            #pragma unroll
            for (int e = 0; e < 4; ++e) {
                int row = mt * 128 + wm + r * 16 + q * 4 + e;      // d
                int col = nt * 128 + wn + c * 16 + ln16;           // n
                ob[(long)row * 256 + col] = f2b(acc[r][c][e]);
            }
}

// ---------------------------------------------------------------------------
// PREFIX: in-place exclusive prefix over 8 chunks (slab loads prefetched).
__global__ __launch_bounds__(256) void prefix_k(unsigned short* __restrict__ Ct) {
    int z = blockIdx.x, dg = blockIdx.y;
    int d = dg * 8 + (threadIdx.x >> 5);
    int n0 = (threadIdx.x & 31) * 8;
    long base = ((long)z * 8) * 512 * 256 + (long)d * 256 + n0;
    constexpr long S = 512 * 256;
    us8 vals[8];
    #pragma unroll
    for (int i = 0; i < 8; ++i)
        vals[i] = *(const us8*)&Ct[base + (long)i * S];
    float acc[8] = {};
    #pragma unroll
    for (int i = 0; i < 8; ++i) {
        us8 o;
        #pragma unroll
        for (int e = 0; e < 8; ++e) o[e] = f2b(acc[e]);
        *(us8*)&Ct[base + (long)i * S] = o;
        #pragma unroll
        for (int e = 0; e < 8; ++e) acc[e] += b2f(vals[i][e]);
    }
}

// ---------------------------------------------------------------------------
// SDIAG (CHUNK=256), 2-phase: 3 quadrants of strict_tril(QR_i @ QR_i^T).
// qq=0 -> (0,0) masked, qq=1 -> (1,0) dense, qq=2 -> (1,1) masked.
// grid (16 z, 8 i, 3 qq).
__global__ __launch_bounds__(256) void sdiag(const unsigned short* __restrict__ qr,
                                             unsigned short* __restrict__ Sd) {
    int z = blockIdx.x, i = blockIdx.y, qq = blockIdx.z;
    int qm = (qq + 1) >> 1, qn = qq >> 1;         // (0,0),(1,0),(1,1)
    const unsigned short* Ab =
        qr + ((long)z * T_ + i * 256 + qm * 128) * NL_;
    const unsigned short* Bb =
        qr + ((long)z * T_ + i * 256 + qn * 128) * NL_;
    bool dual = (qm != qn);
    __shared__ unsigned short As[2][128][32];
    __shared__ unsigned short Bs[2][128][32];
    TILE_IDS
    v4f acc[4][4] = {};
    auto stg = [&](int k0, int buf) {
        #pragma unroll
        for (int ci = 0; ci < 2; ++ci) {
            int c = wid * 2 + ci;
            g2l16(Ab + (long)(c * 16 + srl) * NL_ + k0 + scl,
                  (char*)As[buf] + c * 1024);
            if (dual)
                g2l16(Bb + (long)(c * 16 + srl) * NL_ + k0 + scl,
                      (char*)Bs[buf] + c * 1024);
        }
    };
    stg(0, 0);
    __syncthreads();
    int cur = 0;
    for (int k0 = 0; k0 < NL_; k0 += 32) {
        if (k0 + 32 < NL_) stg(k0 + 32, cur ^ 1);
        if (dual) { TILE_MFMA(As[cur], Bs[cur]) }
        else      { TILE_MFMA(As[cur], As[cur]) }
        __syncthreads();
        cur ^= 1;
    }
    unsigned short* ob = Sd + ((long)z * 8 + i) * 65536;
    #pragma unroll
    for (int r = 0; r < 4; ++r)
        #pragma unroll
        for (int c = 0; c < 4; ++c)
            #pragma unroll
            for (int e = 0; e < 4; ++e) {
                int row = wm + r * 16 + q * 4 + e;
                int col = wn + c * 16 + ln16;
                float v = acc[r][c][e];
                if (!dual && row <= col) v = 0.f;   // strict causal (diag quad)
                ob[(qm * 128 + row) * 256 + qn * 128 + col] = f2b(v);
            }
}

// ---------------------------------------------------------------------------
// PXG (CHUNK=256), 2-phase: unnormalized yKV = QR_i @ P_{chunk(i)} +
// Sd-halfstrip @ X.  Seg2 K = 128 or 256 by half.  Emits exact fp32 per-row
// (sum, sumsq) partials.  grid (16 z, 16 i, 4 nt).
__global__ __launch_bounds__(256) void pxg(
    const unsigned short* __restrict__ qr,    // [z][T][NL]
    const unsigned short* __restrict__ Pt,    // [z*8+j][512][256] (prefix)
    const unsigned short* __restrict__ Sd,    // [z*8+j][256][256]
    const unsigned short* __restrict__ xsT,   // [B][D][T]
    unsigned short* __restrict__ ykvu,        // [NH][BT][D] (unnormalized)
    float* __restrict__ part) {               // [z*16+i][4][128][2]
    int z = blockIdx.x, i = blockIdx.y, nt = blockIdx.z;
    int b = z >> 3, h = z & 7;
    int n0 = nt * 128;
    int i256 = i >> 1, hf2 = i & 1;
    const unsigned short* A1 = qr + ((long)z * T_ + i * 128) * NL_;
    const unsigned short* B1 =
        Pt + ((long)z * 8 + i256) * 512 * 256 + (long)n0 * 256;
    const unsigned short* A2 = Sd + ((long)z * 8 + i256) * 65536 +
                               (long)hf2 * 128 * 256;
    const unsigned short* B2 =
        xsT + (long)b * D_ * T_ + (long)n0 * T_ + i256 * 256;
    __shared__ unsigned short As[2][128][32];   // 16 KB
    __shared__ unsigned short Bs[2][128][32];   // 16 KB
    __shared__ float sred[128][2][2];           //  2 KB
    TILE_IDS
    v4f acc[4][4] = {};
    int NS = 12 + hf2 * 4;   // 8 seg1 steps + 4 or 8 seg2 steps
    auto stage = [&](int s) {
        const unsigned short* Ap;
        const unsigned short* Bp;
        long lda, ldb;
        int k0;
        if (s < 8) { Ap = A1; lda = NL_; Bp = B1; ldb = 256; k0 = s * 32; }
        else       { Ap = A2; lda = 256; Bp = B2; ldb = T_;  k0 = (s - 8) * 32; }
        int bi = s & 1;
        #pragma unroll
        for (int ci = 0; ci < 4; ++ci) {
            int c = wid * 4 + ci;
            if (c < 8)
                g2l16(Ap + (long)(c * 16 + srl) * lda + k0 + scl,
                      (char*)As[bi] + c * 1024);
            else
                g2l16(Bp + (long)((c - 8) * 16 + srl) * ldb + k0 + scl,
                      (char*)Bs[bi] + (c - 8) * 1024);
        }
    };
    stage(0);
    __syncthreads();
    for (int s = 0; s < NS; ++s) {
        if (s + 1 < NS) stage(s + 1);
        int bi = s & 1;
        TILE_MFMA(As[bi], Bs[bi])
        __syncthreads();
    }
    // ---- bf16 store + exact row partial sums (fp32 from accumulators) ----
    long obase = ((long)h * BT_ + (long)b * T_ + i * 128) * D_ + n0;
    #pragma unroll
    for (int r = 0; r < 4; ++r) {
        float s1[4] = {}, s2[4] = {};
        #pragma unroll
        for (int c = 0; c < 4; ++c)
            #pragma unroll
            for (int e = 0; e < 4; ++e) {
                float v = acc[r][c][e];
                s1[e] += v;
                s2[e] += v * v;
                int rl = wm + r * 16 + q * 4 + e;
                int col = wn + c * 16 + ln16;
                ykvu[obase + (long)rl * D_ + col] = f2b(v);
            }
        #pragma unroll
        for (int e = 0; e < 4; ++e) {
            #pragma unroll
            for (int off = 1; off < 16; off <<= 1) {
                s1[e] += __shfl_xor(s1[e], off, 64);
                s2[e] += __shfl_xor(s2[e], off, 64);
            }
            if (ln16 == 0) {
                int rl = wm + r * 16 + q * 4 + e;
                sred[rl][wid >> 1][0] = s1[e];
                sred[rl][wid >> 1][1] = s2[e];
            }
        }
    }
    __syncthreads();
    if (tid < 128) {
        float a = sred[tid][0][0] + sred[tid][1][0];
        float sq = sred[tid][0][1] + sred[tid][1][1];
        long pb = ((((long)z * 16 + i) * 4 + nt) * 128 + tid) * 2;
        part[pb] = a;
        part[pb + 1] = sq;
    }
}

// ---------------------------------------------------------------------------
// LNSTATS: fold pxg's 4 nt-quadrant partials into per-row (mu, inv).
__global__ __launch_bounds__(128) void lnstats(const float* __restrict__ part,
                                               float* __restrict__ muinv) {
    int z = blockIdx.x, i = blockIdx.y, t = threadIdx.x;
    long pb = ((((long)z * 16 + i) * 4) * 128 + t) * 2;
    float s1 = part[pb] + part[pb + 256] + part[pb + 512] + part[pb + 768];
    float s2 = part[pb + 1] + part[pb + 257] + part[pb + 513] + part[pb + 769];
    float mu = s1 * (1.0f / 512.0f);
    float var = s2 * (1.0f / 512.0f) - mu * mu;
    float inv = rsqrtf(var + 1e-5f);
    int b = z >> 3, h = z & 7;
    long row = (long)h * BT_ + (long)b * T_ + i * 128 + t;
    muinv[row * 2]     = mu;
    muinv[row * 2 + 1] = inv;
}

// ---------------------------------------------------------------------------
// COLSUM: colsum[g] = sum_d encvT[g][d] (fp32), g in [0, HN).  One wave/row.
__global__ __launch_bounds__(256) void colsum_k(
    const unsigned short* __restrict__ encvT, float* __restrict__ cs) {
    int lane = threadIdx.x & 63, wv = threadIdx.x >> 6;
    int g = blockIdx.x * 4 + wv;
    us8 v = *(const us8*)&encvT[(long)g * 512 + lane * 8];
    float s = 0.f;
    #pragma unroll
    for (int e = 0; e < 8; ++e) s += b2f(v[e]);
    #pragma unroll
    for (int off = 1; off < 64; off <<= 1) s += __shfl_xor(s, off, 64);
    if (lane == 0) cs[g] = s;
}

// ---------------------------------------------------------------------------
// Transpose + cast fp32 -> bf16: out[Cc][R] = (bf16) in[R][Cc], batched.
__global__ __launch_bounds__(256) void trans_cast(
    const float* __restrict__ in, long sIn, unsigned short* __restrict__ out,
    long sOut, int R, int Cc) {
    __shared__ float tl[32][33];
    int z = blockIdx.z;
    int r0 = blockIdx.y * 32, c0 = blockIdx.x * 32;
    int tx = threadIdx.x & 31, ty = threadIdx.x >> 5;
    const float* ip = in + (long)z * sIn;
    unsigned short* op = out + (long)z * sOut;
    #pragma unroll
    for (int j = 0; j < 4; ++j)
        tl[ty + j * 8][tx] = ip[(long)(r0 + ty + j * 8) * Cc + c0 + tx];
    __syncthreads();
    #pragma unroll
    for (int j = 0; j < 4; ++j)
        op[(long)(c0 + ty + j * 8) * R + r0 + tx] = f2b(tl[tx][ty + j * 8]);
}

// bf16 transpose (no cast): out[Cc][R] = in[R][Cc], batched.  Bitwise
// identical to trans_cast when in == f2b(source) elementwise.
__global__ __launch_bounds__(256) void trans16(
    const unsigned short* __restrict__ in, long sIn,
    unsigned short* __restrict__ out, long sOut, int R, int Cc) {
    __shared__ unsigned short tl[32][34];
    int z = blockIdx.z;
    int r0 = blockIdx.y * 32, c0 = blockIdx.x * 32;
    int tx = threadIdx.x & 31, ty = threadIdx.x >> 5;
    const unsigned short* ip = in + (long)z * sIn;
    unsigned short* op = out + (long)z * sOut;
    #pragma unroll
    for (int j = 0; j < 4; ++j)
        tl[ty + j * 8][tx] = ip[(long)(r0 + ty + j * 8) * Cc + c0 + tx];
    __syncthreads();
    #pragma unroll
    for (int j = 0; j < 4; ++j)
        op[(long)(c0 + ty + j * 8) * R + r0 + tx] = tl[tx][ty + j * 8];
}

// fp32 -> bf16 elementwise (n multiple of 1024)
__global__ __launch_bounds__(256) void cast_b(const float* __restrict__ in,
                                              unsigned short* __restrict__ out) {
    long i = ((long)blockIdx.x * 256 + threadIdx.x) * 4;
    float4 v = *(const float4*)&in[i];
    ushort4 o;
    o.x = f2b(v.x); o.y = f2b(v.y); o.z = f2b(v.z); o.w = f2b(v.w);
    *(ushort4*)&out[i] = o;
}

// out = t0+t1+t2+t3 + bias (4 split-K slices, rows of 512)
__global__ __launch_bounds__(256) void add_out4(const float* __restrict__ t,
                                                long slice,
                                                const float* __restrict__ bias,
                                                float* __restrict__ o) {
    long i = ((long)blockIdx.x * 256 + threadIdx.x) * 4;
    float4 v0 = *(const float4*)&t[i];
    float4 v1 = *(const float4*)&t[i + slice];
    float4 v2 = *(const float4*)&t[i + 2 * slice];
    float4 v3 = *(const float4*)&t[i + 3 * slice];
    float4 bv = *(const float4*)&bias[i & 511];
    float4 r;
    r.x = v0.x + v1.x + v2.x + v3.x + bv.x;
    r.y = v0.y + v1.y + v2.y + v3.y + bv.y;
    r.z = v0.z + v1.z + v2.z + v3.z + bv.z;
    r.w = v0.w + v1.w + v2.w + v3.w + bv.w;
    *(float4*)&o[i] = r;
}

// ---------------------------------------------------------------------------
// LayerNorm helpers (rows of 512, 256 threads, float2 per thread)
__device__ inline float2 block_reduce2(float a, float b) {
    __shared__ float sa[4], sb[4];
    #pragma unroll
    for (int off = 32; off; off >>= 1) {
        a += __shfl_down(a, off, 64);
        b += __shfl_down(b, off, 64);
    }
    __syncthreads();
    int w = threadIdx.x >> 6;
    if ((threadIdx.x & 63) == 0) { sa[w] = a; sb[w] = b; }
    __syncthreads();
    return make_float2(sa[0] + sa[1] + sa[2] + sa[3],
                       sb[0] + sb[1] + sb[2] + sb[3]);
}
__device__ inline float2 ln_pair(float2 v) {
    float2 s = block_reduce2(v.x + v.y, 0.f);
    float mu = s.x * (1.0f / 512.0f);
    float dx = v.x - mu, dy = v.y - mu;
    float2 q = block_reduce2(dx * dx + dy * dy, 0.f);
    float inv = rsqrtf(q.x * (1.0f / 512.0f) + 1e-5f);
    return make_float2(dx * inv, dy * inv);
}

// LN(sum of 4 slices + bias) -> fp32 + bf16
__global__ __launch_bounds__(256) void ln_dual4(const float* __restrict__ t,
                                                long slice,
                                                const float* __restrict__ bias,
                                                float* __restrict__ outf,
                                                unsigned short* __restrict__ outb) {
    long row = blockIdx.x;
    int c = threadIdx.x * 2;
    long i = row * 512 + c;
    float2 v0 = *(const float2*)&t[i];
    float2 v1 = *(const float2*)&t[i + slice];
    float2 v2 = *(const float2*)&t[i + 2 * slice];
    float2 v3 = *(const float2*)&t[i + 3 * slice];
    float2 bv = *(const float2*)&bias[c];
    float2 v = make_float2(v0.x + v1.x + v2.x + v3.x + bv.x,
                           v0.y + v1.y + v2.y + v3.y + bv.y);
    float2 o = ln_pair(v);
    *(float2*)&outf[i] = o;
    ushort2 ob; ob.x = f2b(o.x); ob.y = f2b(o.y);
    *(ushort2*)&outb[i] = ob;
}

// xs_next = LN(x_res + LN(sum of 4 ymlp slices)) -> fp32 + bf16
__global__ __launch_bounds__(256) void combine_dual4(
    const float* __restrict__ t, long slice, const float* __restrict__ xres,
    float* __restrict__ outf, unsigned short* __restrict__ outb) {
    long row = blockIdx.x;
    int c = threadIdx.x * 2;
    long i = row * 512 + c;
    float2 v0 = *(const float2*)&t[i];
    float2 v1 = *(const float2*)&t[i + slice];
    float2 v2 = *(const float2*)&t[i + 2 * slice];
    float2 v3 = *(const float2*)&t[i + 3 * slice];
    float2 y = make_float2(v0.x + v1.x + v2.x + v3.x,
                           v0.y + v1.y + v2.y + v3.y);
    float2 l = ln_pair(y);
    float2 r = *(const float2*)&xres[i];
    float2 z = make_float2(r.x + l.x, r.y + l.y);
    float2 o = ln_pair(z);
    *(float2*)&outf[i] = o;
    ushort2 ob; ob.x = f2b(o.x); ob.y = f2b(o.y);
    *(ushort2*)&outb[i] = ob;
}

// ---------------------------------------------------------------------------
extern "C" void kernel_launch(void* const* d_in, const int* in_sizes, int n_in,
                              void* d_out, int out_size, void* d_ws,
                              size_t ws_size, hipStream_t stream) {
    const float* x      = (const float*)d_in[0];
    const float* w_in   = (const float*)d_in[1];
    const float* b_in   = (const float*)d_in[2];
    const float* enc    = (const float*)d_in[3];
    const float* enc_v  = (const float*)d_in[4];
    const float* dec    = (const float*)d_in[5];
    const float* head_w = (const float*)d_in[6];
    const float* head_b = (const float*)d_in[7];
    float* out = (float*)d_out;

    // ---- workspace (~170 MB) ----
    char* w = (char*)d_ws;
    auto alloc = [&](size_t bytes) { void* p = (void*)w; w += bytes; return p; };
    unsigned short* w_inT = (unsigned short*)alloc((size_t)512 * 512 * 2);
    unsigned short* headT = (unsigned short*)alloc((size_t)512 * 512 * 2);
    unsigned short* encT  = (unsigned short*)alloc((size_t)NH_ * NL_ * D_ * 2);
    unsigned short* encvT = (unsigned short*)alloc((size_t)NH_ * NL_ * D_ * 2);
    unsigned short* decT  = (unsigned short*)alloc((size_t)D_ * HN_ * 2);
    unsigned short* xb    = (unsigned short*)alloc((size_t)BT_ * D_ * 2);
    float*          tmp   = (float*)alloc((size_t)4 * BT_ * D_ * 4);  // 4 K-slices
    float*          xsf0  = (float*)alloc((size_t)BT_ * D_ * 4);
    float*          xsf1  = (float*)alloc((size_t)BT_ * D_ * 4);
    unsigned short* xs_b  = (unsigned short*)alloc((size_t)BT_ * D_ * 2);
    unsigned short* xsT   = (unsigned short*)alloc((size_t)B_ * D_ * T_ * 2);
    unsigned short* xsp   = (unsigned short*)alloc((size_t)BT_ * HN_ * 2);
    unsigned short* qrh   = (unsigned short*)alloc((size_t)BT_ * HN_ * 2);
    unsigned short* qrT   = (unsigned short*)alloc((size_t)BT_ * HN_ * 2);
    unsigned short* Ct    = (unsigned short*)alloc((size_t)128 * 512 * 256 * 2); // 33.5 MB
    unsigned short* Sd    = (unsigned short*)alloc((size_t)128 * 256 * 256 * 2); // 16.8 MB
    unsigned short* ykv   = (unsigned short*)alloc((size_t)NH_ * BT_ * D_ * 2);
    float*          part  = (float*)alloc((size_t)256 * 4 * 128 * 2 * 4);        //  1 MB
    float*          muinv = (float*)alloc((size_t)NH_ * BT_ * 2 * 4);            // 256 KB
    float*          csum  = (float*)alloc((size_t)HN_ * 4);                      //   8 KB
    const long SL = (long)BT_ * D_;   // split-K slice stride (elements)

    // ---- prep ----
    cast_b<<<BT_ * D_ / 1024, 256, 0, stream>>>(x, xb);
    trans_cast<<<dim3(16, 16, 1), 256, 0, stream>>>(w_in, 0, w_inT, 0, 512, 512);
    trans_cast<<<dim3(16, 16, 1), 256, 0, stream>>>(head_w, 0, headT, 0, 512, 512);
    trans_cast<<<dim3(8, 16, 8), 256, 0, stream>>>(enc, (long)D_ * NL_, encT,
                                                   (long)NL_ * D_, D_, NL_);
    trans_cast<<<dim3(8, 16, 8), 256, 0, stream>>>(enc_v, (long)D_ * NL_, encvT,
                                                   (long)NL_ * D_, D_, NL_);
    trans_cast<<<dim3(16, 64, 1), 256, 0, stream>>>(dec, 0, decT, 0, HN_, D_);
    colsum_k<<<HN_ / 4, 256, 0, stream>>>(encvT, csum);

    // ---- xs = LN(x @ w_in + b_in)  (split-K=4) ----
    gemm128<64, false, false, false, false>
        <<<dim3(4, 32, 4), 256, 0, stream>>>(xb, D_, 128, w_inT, D_, 128, tmp,
                                             D_, SL, nullptr, 128, nullptr,
                                             nullptr);
    ln_dual4<<<BT_, 256, 0, stream>>>(tmp, SL, b_in, xsf0, xs_b);
    trans16<<<dim3(16, 64, 2), 256, 0, stream>>>(xs_b, (long)T_ * D_, xsT,
                                                 (long)D_ * T_, T_, D_);

    float* xin = xsf0;
    float* xout = xsf1;
    for (int l = 0; l < 3; ++l) {
        // x_sparse + rope + both QR layouts, one kernel (counted-vmcnt pipe)
        enc_rope<<<dim3(16, 32), 256, 0, stream>>>(xs_b, encT, xsp, qrh, qrT);
        // linear-attention state tiles (chunk 256): Ct[z][j] = X_j^T @ QR_j
        ct_gemm<<<dim3(16, 2, 32), 256, 0, stream>>>(xsT, qrT, Ct);
        // exclusive prefix over 8 chunks (in place)
        prefix_k<<<dim3(16, 64), 256, 0, stream>>>(Ct);
        // diagonal strict 256x256 scores (3 quadrants)
        sdiag<<<dim3(16, 8, 3), 256, 0, stream>>>(qrh, Sd);
        // yKV(unnorm) = QR_i @ P + Sd-half @ X  + row stats
        pxg<<<dim3(16, 16, 4), 256, 0, stream>>>(qrh, Ct, Sd, xsT, ykv, part);
        // fold partials -> per-row (mu, inv)
        lnstats<<<dim3(16, 16), 128, 0, stream>>>(part, muinv);
        // xy = relu(LN(yKV)[h] @ enc_v[h]) * x_sparse, LN folded via linearity
        gemm128<64, true, true, true, true>
            <<<dim3(2, 32, 8), 256, 0, stream>>>(
                ykv, D_, (long)BT_ * D_, encvT, D_, (long)NL_ * D_, xsp, HN_,
                NL_, xsp, 512, muinv, csum);
        // yMLP = xy @ decoder  (split-K=4) -> fp32 slices
        gemm128<64, false, false, false, false>
            <<<dim3(4, 32, 4), 256, 0, stream>>>(
                xsp, HN_, 512, decT, HN_, 512, tmp, D_, SL, nullptr, 512,
                nullptr, nullptr);
        // xs = LN(x_res + LN(yMLP))
        combine_dual4<<<BT_, 256, 0, stream>>>(tmp, SL, xin, xout, xs_b);
        trans16<<<dim3(16, 64, 2), 256, 0, stream>>>(xs_b, (long)T_ * D_, xsT,
                                                     (long)D_ * T_, T_, D_);
        float* t = xin; xin = xout; xout = t;
    }

    // logits = xs @ head_w + head_b  (split-K=4)
    gemm128<64, false, false, false, false>
        <<<dim3(4, 32, 4), 256, 0, stream>>>(xs_b, D_, 128, headT, D_, 128, tmp,
                                             D_, SL, nullptr, 128, nullptr,
                                             nullptr);
    add_out4<<<BT_ * 512 / 1024, 256, 0, stream>>>(tmp, SL, head_b, out);
}

// Round 18
// 550.125 us; speedup vs baseline: 1.1731x; 1.0862x over previous
//
#include <hip/hip_runtime.h>
#include <math.h>

constexpr int B_  = 2;
constexpr int T_  = 2048;
constexpr int D_  = 512;
constexpr int NH_ = 8;
constexpr int NL_ = 256;
constexpr int HN_ = NH_ * NL_;   // 2048
constexpr int BT_ = B_ * T_;     // 4096

typedef __bf16 v8bf __attribute__((ext_vector_type(8)));
typedef float  v4f  __attribute__((ext_vector_type(4)));
typedef unsigned short us8 __attribute__((ext_vector_type(8)));
typedef unsigned short us4 __attribute__((ext_vector_type(4)));

__device__ inline unsigned short f2b(float f) {
    union { float f; unsigned u; } v{f};
    unsigned r = v.u + 0x7FFF + ((v.u >> 16) & 1);   // rtne
    return (unsigned short)(r >> 16);
}
__device__ inline float b2f(unsigned short u) {
    union { unsigned u; float f; } v{(unsigned)u << 16};
    return v.f;
}

// async 16B global->LDS (per-lane gaddr; LDS dest = wave-uniform base + lane*16)
__device__ __forceinline__ void g2l16(const void* g, void* l) {
    __builtin_amdgcn_global_load_lds(
        (const __attribute__((address_space(1))) void*)g,
        (__attribute__((address_space(3))) void*)l, 16, 0, 0);
}

// counted waits (T4)
#define VMCNT4 asm volatile("s_waitcnt vmcnt(4)" ::: "memory")
#define VMCNT0 asm volatile("s_waitcnt vmcnt(0)" ::: "memory")
#define BARRIER_FENCE                                   \
    __builtin_amdgcn_s_barrier();                       \
    asm volatile("" ::: "memory")

// ===========================================================================
// Shared lane decomposition.
#define TILE_IDS                                              \
    int tid = threadIdx.x;                                    \
    int lane = tid & 63, wid = tid >> 6;                      \
    int wm = (wid & 1) * 64, wn = (wid >> 1) * 64;            \
    int ln16 = lane & 15, q = lane >> 4;                      \
    int srl = lane >> 2, scl = (lane & 3) * 8;                \
    (void)wm; (void)wn;

// 128x128 MFMA step: 4x4 16x16x32 per wave (16 MFMA).
#define TILE_MFMA(Asx, Bsx)                                   \
    {                                                         \
        v8bf af[4], bfr[4];                                   \
        _Pragma("unroll")                                     \
        for (int r = 0; r < 4; ++r)                           \
            af[r] = *(const v8bf*)&Asx[wm + r * 16 + ln16][q * 8]; \
        _Pragma("unroll")                                     \
        for (int c = 0; c < 4; ++c)                           \
            bfr[c] = *(const v8bf*)&Bsx[wn + c * 16 + ln16][q * 8]; \
        _Pragma("unroll")                                     \
        for (int r = 0; r < 4; ++r)                           \
            _Pragma("unroll")                                 \
            for (int c = 0; c < 4; ++c)                       \
                acc[r][c] = __builtin_amdgcn_mfma_f32_16x16x32_bf16( \
                    af[r], bfr[c], acc[r][c], 0, 0, 0);       \
    }

// ---------------------------------------------------------------------------
// Generic 128x128-tile bf16 GEMM: C[M,N] = A[M,K] @ Bt[N,K]^T, z-batched.
// KS = K-step per barrier.  [r16 lesson: keep KS=64 2-phase — BK=32
// counted-vmcnt halved MFMA/barrier and regressed +64us.]
// LNA: LN(A)@B = inv * (A@B - mu * colsum(B)); (mu,inv) computed IN-KERNEL
// from pxg's exact fp32 partials (lnstats fold — bitwise identical).
template <int KS, bool RELU, bool MUL, bool BF16OUT, bool LNA>
__global__ __launch_bounds__(256) void gemm128(
    const unsigned short* __restrict__ A, int lda, long sA,
    const unsigned short* __restrict__ Bt, int ldb, long sB,
    void* __restrict__ Cv, int ldc, long sC,
    const unsigned short* __restrict__ mulp, int K,
    const float* __restrict__ part, const float* __restrict__ colsum) {
    constexpr int NHF = KS / 32;
    int m0 = blockIdx.y * 128, n0 = blockIdx.x * 128, z = blockIdx.z;
    __shared__ unsigned short As[2][NHF][128][32];
    __shared__ unsigned short Bs[2][NHF][128][32];
    __shared__ float muis[128][2];   // 1 KB (LNA only; harmless otherwise)
    const unsigned short* Ab = A  + (long)z * sA + (long)m0 * lda;
    const unsigned short* Bb = Bt + (long)z * sB + (long)n0 * ldb;
    TILE_IDS
    v4f acc[4][4] = {};
    auto stageK = [&](int k0, int buf) {
        #pragma unroll
        for (int h = 0; h < NHF; ++h)
            #pragma unroll
            for (int ci = 0; ci < 4; ++ci) {
                int c = wid * 4 + ci;
                if (c < 8)
                    g2l16(Ab + (long)(c * 16 + srl) * lda + k0 + h * 32 + scl,
                          (char*)As[buf][h] + c * 1024);
                else
                    g2l16(Bb + (long)((c - 8) * 16 + srl) * ldb + k0 + h * 32 +
                              scl,
                          (char*)Bs[buf][h] + (c - 8) * 1024);
            }
    };
    stageK(0, 0);
    if (LNA && tid < 128) {
        // lnstats fold: rows m0..m0+127 = one (z', i) strip of pxg partials
        int bb = m0 >> 11;                 // batch
        int ii = (m0 & (T_ - 1)) >> 7;     // 128-strip index in T
        int zp = bb * 8 + z;               // pxg z = b*8 + h
        long pb = ((((long)zp * 16 + ii) * 4) * 128 + tid) * 2;
        float s1 = part[pb] + part[pb + 256] + part[pb + 512] + part[pb + 768];
        float s2 =
            part[pb + 1] + part[pb + 257] + part[pb + 513] + part[pb + 769];
        float mu = s1 * (1.0f / 512.0f);
        float var = s2 * (1.0f / 512.0f) - mu * mu;
        muis[tid][0] = mu;
        muis[tid][1] = rsqrtf(var + 1e-5f);
    }
    __syncthreads();
    int cur = 0;
    for (int k0 = 0; k0 < K; k0 += KS) {
        if (k0 + KS < K) stageK(k0 + KS, cur ^ 1);
        #pragma unroll
        for (int h = 0; h < NHF; ++h)
            TILE_MFMA(As[cur][h], Bs[cur][h])
        __syncthreads();
        cur ^= 1;
    }
    float* Cf = (float*)Cv;
    unsigned short* Cb = (unsigned short*)Cv;
    long zoff = (long)z * sC;
    #pragma unroll
    for (int r = 0; r < 4; ++r)
        #pragma unroll
        for (int c = 0; c < 4; ++c)
            #pragma unroll
            for (int e = 0; e < 4; ++e) {
                int lrow = wm + r * 16 + q * 4 + e;
                int row = m0 + lrow;
                int col = n0 + wn + c * 16 + ln16;
                float v = acc[r][c][e];
                if (LNA) {
                    float cs = colsum[(long)z * NL_ + col];
                    v = muis[lrow][1] * (v - muis[lrow][0] * cs);
                }
                if (RELU) v = fmaxf(v, 0.f);
                long idx = zoff + (long)row * ldc + col;
                if (MUL) v *= b2f(mulp[idx]);
                if (BF16OUT) Cb[idx] = f2b(v);
                else         Cf[idx] = v;
            }
}

// ---------------------------------------------------------------------------
// ENC+ROPE body (counted-vmcnt pipeline, measured r15): BK=32, 4 LDS bufs
// (64 KB), depth-2 prefetch.  [r13: 128x64 tiles regress — BW-bound.]
__device__ __forceinline__ void enc_body(
    const unsigned short* __restrict__ A,    // xs_b [BT][512]
    const unsigned short* __restrict__ Bt,   // encT [HN][512] K-major
    unsigned short* __restrict__ xsp,        // [BT][HN]
    unsigned short* __restrict__ qrh,        // [z][T][NL]
    unsigned short* __restrict__ qrT,        // [z][NL][T]
    unsigned short* smem, int nt, int mt) {
    int m0 = mt * 128, n0 = nt * 128;
    auto As = (unsigned short(*)[128][32])smem;            // As[4] 32 KB
    auto Bs = (unsigned short(*)[128][32])(smem + 16384);  // Bs[4] 32 KB
    unsigned short (*lt)[136] = (unsigned short(*)[136])smem; // 34.8 KB
    const unsigned short* Ab = A + (long)m0 * 512;
    const unsigned short* Bb = Bt + (long)n0 * 512;
    TILE_IDS
    v4f acc[4][4] = {};
    auto stage = [&](int t) {
        int k0 = t * 32, buf = t & 3;
        #pragma unroll
        for (int ci = 0; ci < 4; ++ci) {
            int c = wid * 4 + ci;
            if (c < 8)
                g2l16(Ab + (long)(c * 16 + srl) * 512 + k0 + scl,
                      (char*)As[buf] + c * 1024);
            else
                g2l16(Bb + (long)((c - 8) * 16 + srl) * 512 + k0 + scl,
                      (char*)Bs[buf] + (c - 8) * 1024);
        }
    };
    stage(0);
    stage(1);
#define ER_STEP(T, W)                                           \
    W;                                                          \
    BARRIER_FENCE;                                              \
    if ((T) + 2 < 16) stage((T) + 2);                           \
    TILE_MFMA(As[(T) & 3], Bs[(T) & 3])
    ER_STEP(0, VMCNT4)  ER_STEP(1, VMCNT4)  ER_STEP(2, VMCNT4)
    ER_STEP(3, VMCNT4)  ER_STEP(4, VMCNT4)  ER_STEP(5, VMCNT4)
    ER_STEP(6, VMCNT4)  ER_STEP(7, VMCNT4)  ER_STEP(8, VMCNT4)
    ER_STEP(9, VMCNT4)  ER_STEP(10, VMCNT4) ER_STEP(11, VMCNT4)
    ER_STEP(12, VMCNT4) ER_STEP(13, VMCNT4) ER_STEP(14, VMCNT4)
    ER_STEP(15, VMCNT0)
#undef ER_STEP
    __syncthreads();   // all MFMA done; LDS buffers dead -> lt overlay safe
    int bb = m0 >> 11;                  // batch
    int tbase = m0 & (T_ - 1);
    #pragma unroll
    for (int r = 0; r < 4; ++r)
        #pragma unroll
        for (int c = 0; c < 4; ++c)
            #pragma unroll
            for (int e = 0; e < 4; ++e) {
                int rl = wm + r * 16 + q * 4 + e;        // t-local 0..127
                int col = n0 + wn + c * 16 + ln16;
                float v = fmaxf(acc[r][c][e], 0.f);
                xsp[(long)(m0 + rl) * HN_ + col] = f2b(v);
                int n = col & (NL_ - 1);
                int n2 = n >> 1;
                float fr = exp2f(-(float)n2 * 0.125f) *
                           (float)(1.0 / (2.0 * M_PI));
                float ph = (float)(tbase + rl) * fr;
                ph = (ph - floorf(ph)) * (float)(2.0 * M_PI);
                float s, cc;
                __sincosf(ph, &s, &cc);
                float vp = __shfl_xor(v, 1, 64);   // partner col^1
                float o = (n & 1) ? (v * cc + vp * s) : (v * cc - vp * s);
                int hh = col >> 8;
                qrh[((long)(bb * 8 + hh) * T_ + tbase + rl) * NL_ + n] = f2b(o);
                lt[wn + c * 16 + ln16][rl] = f2b(o);
            }
    __syncthreads();
    {
        int nrow = tid >> 1, tseg = (tid & 1) * 64;
        int colg = n0 + nrow;
        int hh = colg >> 8, nn = colg & (NL_ - 1);
        long ob = ((long)(bb * 8 + hh) * NL_ + nn) * T_ + tbase + tseg;
        #pragma unroll
        for (int u = 0; u < 16; ++u)
            *(us4*)&qrT[ob + u * 4] = *(const us4*)&lt[nrow][tseg + u * 4];
    }
}

// bf16 32x32-tile transpose body (bitwise = old trans16): out[c][r]=in[r][c].
__device__ __forceinline__ void tr_body(const unsigned short* __restrict__ in,
                                        unsigned short* __restrict__ out,
                                        unsigned short* smem, int tb) {
    unsigned short (*tl)[34] = (unsigned short(*)[34])smem;
    int x = tb & 15, y = (tb >> 4) & 63, zz = tb >> 10;
    int r0 = y * 32, c0 = x * 32;
    int tx = threadIdx.x & 31, ty = threadIdx.x >> 5;
    const unsigned short* ip = in + (long)zz * T_ * D_;
    unsigned short* op = out + (long)zz * D_ * T_;
    #pragma unroll
    for (int j = 0; j < 4; ++j)
        tl[ty + j * 8][tx] = ip[(long)(r0 + ty + j * 8) * D_ + c0 + tx];
    __syncthreads();
    #pragma unroll
    for (int j = 0; j < 4; ++j)
        op[(long)(c0 + ty + j * 8) * T_ + r0 + tx] = tl[tx][ty + j * 8];
}

// MERGED launch: enc_rope (blocks 0..511, heavy, dispatched first) +
// xs_b->xsT transpose (blocks 512..2559).  Independent work, shared LDS pool.
__global__ __launch_bounds__(256) void enc_tr(
    const unsigned short* __restrict__ A, const unsigned short* __restrict__ Bt,
    unsigned short* __restrict__ xsp, unsigned short* __restrict__ qrh,
    unsigned short* __restrict__ qrT, unsigned short* __restrict__ xsT) {
    __shared__ unsigned short smem[32768];   // 64 KB
    int bid = blockIdx.x;
    if (bid < 512)
        enc_body(A, Bt, xsp, qrh, qrT, smem, bid & 15, bid >> 4);
    else
        tr_body(A, xsT, smem, bid - 512);
}

// ---------------------------------------------------------------------------
// CT-GEMM body (CHUNK=256, 2-phase BK=32): Ct[z][j][d][n] = X_j^T @ QR_j.
__device__ __forceinline__ void ct_body(
    const unsigned short* __restrict__ xsT, const unsigned short* __restrict__ qrT,
    unsigned short* __restrict__ Ct, unsigned short* smem,
    int z, int nt, int jm) {
    int j = jm >> 2, mt = jm & 3;
    int b = z >> 3;
    auto As = (unsigned short(*)[128][32])smem;            // 16 KB
    auto Bs = (unsigned short(*)[128][32])(smem + 8192);   // 16 KB
    const unsigned short* Ab =
        xsT + (long)b * D_ * T_ + (long)(mt * 128) * T_ + j * 256;
    const unsigned short* Bb =
        qrT + (long)z * NL_ * T_ + (long)(nt * 128) * T_ + j * 256;
    TILE_IDS
    v4f acc[4][4] = {};
    auto stg = [&](int k0, int buf) {
        #pragma unroll
        for (int ci = 0; ci < 4; ++ci) {
            int c = wid * 4 + ci;
            if (c < 8)
                g2l16(Ab + (long)(c * 16 + srl) * T_ + k0 + scl,
                      (char*)As[buf] + c * 1024);
            else
                g2l16(Bb + (long)((c - 8) * 16 + srl) * T_ + k0 + scl,
                      (char*)Bs[buf] + (c - 8) * 1024);
        }
    };
    stg(0, 0);
    __syncthreads();
    int cur = 0;
    for (int k0 = 0; k0 < 256; k0 += 32) {
        if (k0 + 32 < 256) stg(k0 + 32, cur ^ 1);
        TILE_MFMA(As[cur], Bs[cur])
        __syncthreads();
        cur ^= 1;
    }
    unsigned short* ob = Ct + ((long)z * 8 + j) * 512 * 256;
    #pragma unroll
    for (int r = 0; r < 4; ++r)
        #pragma unroll
        for (int c = 0; c < 4; ++c)
            #pragma unroll
            for (int e = 0; e < 4; ++e) {
                int row = mt * 128 + wm + r * 16 + q * 4 + e;      // d
                int col = nt * 128 + wn + c * 16 + ln16;           // n
                ob[(long)row * 256 + col] = f2b(acc[r][c][e]);
            }
}

// SDIAG body (CHUNK=256, 2-phase): quadrant qq of strict_tril(QR_i@QR_i^T).
__device__ __forceinline__ void sd_body(const unsigned short* __restrict__ qr,
                                        unsigned short* __restrict__ Sd,
                                        unsigned short* smem,
                                        int z, int i, int qq) {
    int qm = (qq + 1) >> 1, qn = qq >> 1;         // (0,0),(1,0),(1,1)
    auto As = (unsigned short(*)[128][32])smem;
    auto Bs = (unsigned short(*)[128][32])(smem + 8192);
    const unsigned short* Ab =
        qr + ((long)z * T_ + i * 256 + qm * 128) * NL_;
    const unsigned short* Bb =
        qr + ((long)z * T_ + i * 256 + qn * 128) * NL_;
    bool dual = (qm != qn);
    TILE_IDS
    v4f acc[4][4] = {};
    auto stg = [&](int k0, int buf) {
        #pragma unroll
        for (int ci = 0; ci < 2; ++ci) {
            int c = wid * 2 + ci;
            g2l16(Ab + (long)(c * 16 + srl) * NL_ + k0 + scl,
                  (char*)As[buf] + c * 1024);
            if (dual)
                g2l16(Bb + (long)(c * 16 + srl) * NL_ + k0 + scl,
                      (char*)Bs[buf] + c * 1024);
        }
    };
    stg(0, 0);
    __syncthreads();
    int cur = 0;
    for (int k0 = 0; k0 < NL_; k0 += 32) {
        if (k0 + 32 < NL_) stg(k0 + 32, cur ^ 1);
        if (dual) { TILE_MFMA(As[cur], Bs[cur]) }
        else      { TILE_MFMA(As[cur], As[cur]) }
        __syncthreads();
        cur ^= 1;
    }
    unsigned short* ob = Sd + ((long)z * 8 + i) * 65536;
    #pragma unroll
    for (int r = 0; r < 4; ++r)
        #pragma unroll
        for (int c = 0; c < 4; ++c)
            #pragma unroll
            for (int e = 0; e < 4; ++e) {
                int row = wm + r * 16 + q * 4 + e;
                int col = wn + c * 16 + ln16;
                float v = acc[r][c][e];
                if (!dual && row <= col) v = 0.f;   // strict causal (diag quad)
                ob[(qm * 128 + row) * 256 + qn * 128 + col] = f2b(v);
            }
}

// MERGED launch: ct_gemm (blocks 0..1023) + sdiag (blocks 1024..1407).
// Independent outputs (Ct vs Sd); both read enc_tr products.
__global__ __launch_bounds__(256) void ct_sd(
    const unsigned short* __restrict__ xsT,
    const unsigned short* __restrict__ qrT,
    const unsigned short* __restrict__ qrh,
    unsigned short* __restrict__ Ct, unsigned short* __restrict__ Sd) {
    __shared__ unsigned short smem[16384];   // 32 KB
    int bid = blockIdx.x;
    if (bid < 1024)
        ct_body(xsT, qrT, Ct, smem, bid & 15, (bid >> 4) & 1, bid >> 5);
    else {
        int sid = bid - 1024;
        sd_body(qrh, Sd, smem, sid & 15, (sid >> 4) & 7, sid >> 7);
    }
}

// ---------------------------------------------------------------------------
// PREFIX: in-place exclusive prefix over 8 chunks (slab loads prefetched).
__global__ __launch_bounds__(256) void prefix_k(unsigned short* __restrict__ Ct) {
    int z = blockIdx.x, dg = blockIdx.y;
    int d = dg * 8 + (threadIdx.x >> 5);
    int n0 = (threadIdx.x & 31) * 8;
    long base = ((long)z * 8) * 512 * 256 + (long)d * 256 + n0;
    constexpr long S = 512 * 256;
    us8 vals[8];
    #pragma unroll
    for (int i = 0; i < 8; ++i)
        vals[i] = *(const us8*)&Ct[base + (long)i * S];
    float acc[8] = {};
    #pragma unroll
    for (int i = 0; i < 8; ++i) {
        us8 o;
        #pragma unroll
        for (int e = 0; e < 8; ++e) o[e] = f2b(acc[e]);
        *(us8*)&Ct[base + (long)i * S] = o;
        #pragma unroll
        for (int e = 0; e < 8; ++e) acc[e] += b2f(vals[i][e]);
    }
}

// ---------------------------------------------------------------------------
// PXG (CHUNK=256), 2-phase: unnormalized yKV = QR_i @ P_{chunk(i)} +
// Sd-halfstrip @ X.  Emits exact fp32 per-row (sum, sumsq) partials.
// grid (16 z, 16 i, 4 nt).
__global__ __launch_bounds__(256) void pxg(
    const unsigned short* __restrict__ qr,    // [z][T][NL]
    const unsigned short* __restrict__ Pt,    // [z*8+j][512][256] (prefix)
    const unsigned short* __restrict__ Sd,    // [z*8+j][256][256]
    const unsigned short* __restrict__ xsT,   // [B][D][T]
    unsigned short* __restrict__ ykvu,        // [NH][BT][D] (unnormalized)
    float* __restrict__ part) {               // [z*16+i][4][128][2]
    int z = blockIdx.x, i = blockIdx.y, nt = blockIdx.z;
    int b = z >> 3, h = z & 7;
    int n0 = nt * 128;
    int i256 = i >> 1, hf2 = i & 1;
    const unsigned short* A1 = qr + ((long)z * T_ + i * 128) * NL_;
    const unsigned short* B1 =
        Pt + ((long)z * 8 + i256) * 512 * 256 + (long)n0 * 256;
    const unsigned short* A2 = Sd + ((long)z * 8 + i256) * 65536 +
                               (long)hf2 * 128 * 256;
    const unsigned short* B2 =
        xsT + (long)b * D_ * T_ + (long)n0 * T_ + i256 * 256;
    __shared__ unsigned short As[2][128][32];   // 16 KB
    __shared__ unsigned short Bs[2][128][32];   // 16 KB
    __shared__ float sred[128][2][2];           //  2 KB
    TILE_IDS
    v4f acc[4][4] = {};
    int NS = 12 + hf2 * 4;   // 8 seg1 steps + 4 or 8 seg2 steps
    auto stage = [&](int s) {
        const unsigned short* Ap;
        const unsigned short* Bp;
        long lda, ldb;
        int k0;
        if (s < 8) { Ap = A1; lda = NL_; Bp = B1; ldb = 256; k0 = s * 32; }
        else       { Ap = A2; lda = 256; Bp = B2; ldb = T_;  k0 = (s - 8) * 32; }
        int bi = s & 1;
        #pragma unroll
        for (int ci = 0; ci < 4; ++ci) {
            int c = wid * 4 + ci;
            if (c < 8)
                g2l16(Ap + (long)(c * 16 + srl) * lda + k0 + scl,
                      (char*)As[bi] + c * 1024);
            else
                g2l16(Bp + (long)((c - 8) * 16 + srl) * ldb + k0 + scl,
                      (char*)Bs[bi] + (c - 8) * 1024);
        }
    };
    stage(0);
    __syncthreads();
    for (int s = 0; s < NS; ++s) {
        if (s + 1 < NS) stage(s + 1);
        int bi = s & 1;
        TILE_MFMA(As[bi], Bs[bi])
        __syncthreads();
    }
    // ---- bf16 store + exact row partial sums (fp32 from accumulators) ----
    long obase = ((long)h * BT_ + (long)b * T_ + i * 128) * D_ + n0;
    #pragma unroll
    for (int r = 0; r < 4; ++r) {
        float s1[4] = {}, s2[4] = {};
        #pragma unroll
        for (int c = 0; c < 4; ++c)
            #pragma unroll
            for (int e = 0; e < 4; ++e) {
                float v = acc[r][c][e];
                s1[e] += v;
                s2[e] += v * v;
                int rl = wm + r * 16 + q * 4 + e;
                int col = wn + c * 16 + ln16;
                ykvu[obase + (long)rl * D_ + col] = f2b(v);
            }
        #pragma unroll
        for (int e = 0; e < 4; ++e) {
            #pragma unroll
            for (int off = 1; off < 16; off <<= 1) {
                s1[e] += __shfl_xor(s1[e], off, 64);
                s2[e] += __shfl_xor(s2[e], off, 64);
            }
            if (ln16 == 0) {
                int rl = wm + r * 16 + q * 4 + e;
                sred[rl][wid >> 1][0] = s1[e];
                sred[rl][wid >> 1][1] = s2[e];
            }
        }
    }
    __syncthreads();
    if (tid < 128) {
        float a = sred[tid][0][0] + sred[tid][1][0];
        float sq = sred[tid][0][1] + sred[tid][1][1];
        long pb = ((((long)z * 16 + i) * 4 + nt) * 128 + tid) * 2;
        part[pb] = a;
        part[pb + 1] = sq;
    }
}

// ---------------------------------------------------------------------------
// COLSUM: colsum[g] = sum_d encvT[g][d] (fp32), g in [0, HN).  One wave/row.
__global__ __launch_bounds__(256) void colsum_k(
    const unsigned short* __restrict__ encvT, float* __restrict__ cs) {
    int lane = threadIdx.x & 63, wv = threadIdx.x >> 6;
    int g = blockIdx.x * 4 + wv;
    us8 v = *(const us8*)&encvT[(long)g * 512 + lane * 8];
    float s = 0.f;
    #pragma unroll
    for (int e = 0; e < 8; ++e) s += b2f(v[e]);
    #pragma unroll
    for (int off = 1; off < 64; off <<= 1) s += __shfl_xor(s, off, 64);
    if (lane == 0) cs[g] = s;
}

// ---------------------------------------------------------------------------
// Transpose + cast fp32 -> bf16: out[Cc][R] = (bf16) in[R][Cc], batched.
__global__ __launch_bounds__(256) void trans_cast(
    const float* __restrict__ in, long sIn, unsigned short* __restrict__ out,
    long sOut, int R, int Cc) {
    __shared__ float tl[32][33];
    int z = blockIdx.z;
    int r0 = blockIdx.y * 32, c0 = blockIdx.x * 32;
    int tx = threadIdx.x & 31, ty = threadIdx.x >> 5;
    const float* ip = in + (long)z * sIn;
    unsigned short* op = out + (long)z * sOut;
    #pragma unroll
    for (int j = 0; j < 4; ++j)
        tl[ty + j * 8][tx] = ip[(long)(r0 + ty + j * 8) * Cc + c0 + tx];
    __syncthreads();
    #pragma unroll
    for (int j = 0; j < 4; ++j)
        op[(long)(c0 + ty + j * 8) * R + r0 + tx] = f2b(tl[tx][ty + j * 8]);
}

// fp32 -> bf16 elementwise (n multiple of 1024)
__global__ __launch_bounds__(256) void cast_b(const float* __restrict__ in,
                                              unsigned short* __restrict__ out) {
    long i = ((long)blockIdx.x * 256 + threadIdx.x) * 4;
    float4 v = *(const float4*)&in[i];
    ushort4 o;
    o.x = f2b(v.x); o.y = f2b(v.y); o.z = f2b(v.z); o.w = f2b(v.w);
    *(ushort4*)&out[i] = o;
}

// out = t0+t1+t2+t3 + bias (4 split-K slices, rows of 512)
__global__ __launch_bounds__(256) void add_out4(const float* __restrict__ t,
                                                long slice,
                                                const float* __restrict__ bias,
                                                float* __restrict__ o) {
    long i = ((long)blockIdx.x * 256 + threadIdx.x) * 4;
    float4 v0 = *(const float4*)&t[i];
    float4 v1 = *(const float4*)&t[i + slice];
    float4 v2 = *(const float4*)&t[i + 2 * slice];
    float4 v3 = *(const float4*)&t[i + 3 * slice];
    float4 bv = *(const float4*)&bias[i & 511];
    float4 r;
    r.x = v0.x + v1.x + v2.x + v3.x + bv.x;
    r.y = v0.y + v1.y + v2.y + v3.y + bv.y;
    r.z = v0.z + v1.z + v2.z + v3.z + bv.z;
    r.w = v0.w + v1.w + v2.w + v3.w + bv.w;
    *(float4*)&o[i] = r;
}

// ---------------------------------------------------------------------------
// LayerNorm helpers (rows of 512, 256 threads, float2 per thread)
__device__ inline float2 block_reduce2(float a, float b) {
    __shared__ float sa[4], sb[4];
    #pragma unroll
    for (int off = 32; off; off >>= 1) {
        a += __shfl_down(a, off, 64);
        b += __shfl_down(b, off, 64);
    }
    __syncthreads();
    int w = threadIdx.x >> 6;
    if ((threadIdx.x & 63) == 0) { sa[w] = a; sb[w] = b; }
    __syncthreads();
    return make_float2(sa[0] + sa[1] + sa[2] + sa[3],
                       sb[0] + sb[1] + sb[2] + sb[3]);
}
__device__ inline float2 ln_pair(float2 v) {
    float2 s = block_reduce2(v.x + v.y, 0.f);
    float mu = s.x * (1.0f / 512.0f);
    float dx = v.x - mu, dy = v.y - mu;
    float2 q = block_reduce2(dx * dx + dy * dy, 0.f);
    float inv = rsqrtf(q.x * (1.0f / 512.0f) + 1e-5f);
    return make_float2(dx * inv, dy * inv);
}

// LN(sum of 4 slices + bias) -> fp32 + bf16
__global__ __launch_bounds__(256) void ln_dual4(const float* __restrict__ t,
                                                long slice,
                                                const float* __restrict__ bias,
                                                float* __restrict__ outf,
                                                unsigned short* __restrict__ outb) {
    long row = blockIdx.x;
    int c = threadIdx.x * 2;
    long i = row * 512 + c;
    float2 v0 = *(const float2*)&t[i];
    float2 v1 = *(const float2*)&t[i + slice];
    float2 v2 = *(const float2*)&t[i + 2 * slice];
    float2 v3 = *(const float2*)&t[i + 3 * slice];
    float2 bv = *(const float2*)&bias[c];
    float2 v = make_float2(v0.x + v1.x + v2.x + v3.x + bv.x,
                           v0.y + v1.y + v2.y + v3.y + bv.y);
    float2 o = ln_pair(v);
    *(float2*)&outf[i] = o;
    ushort2 ob; ob.x = f2b(o.x); ob.y = f2b(o.y);
    *(ushort2*)&outb[i] = ob;
}

// xs_next = LN(x_res + LN(sum of 4 ymlp slices)) -> fp32 + bf16
__global__ __launch_bounds__(256) void combine_dual4(
    const float* __restrict__ t, long slice, const float* __restrict__ xres,
    float* __restrict__ outf, unsigned short* __restrict__ outb) {
    long row = blockIdx.x;
    int c = threadIdx.x * 2;
    long i = row * 512 + c;
    float2 v0 = *(const float2*)&t[i];
    float2 v1 = *(const float2*)&t[i + slice];
    float2 v2 = *(const float2*)&t[i + 2 * slice];
    float2 v3 = *(const float2*)&t[i + 3 * slice];
    float2 y = make_float2(v0.x + v1.x + v2.x + v3.x,
                           v0.y + v1.y + v2.y + v3.y);
    float2 l = ln_pair(y);
    float2 r = *(const float2*)&xres[i];
    float2 z = make_float2(r.x + l.x, r.y + l.y);
    float2 o = ln_pair(z);
    *(float2*)&outf[i] = o;
    ushort2 ob; ob.x = f2b(o.x); ob.y = f2b(o.y);
    *(ushort2*)&outb[i] = ob;
}

// ---------------------------------------------------------------------------
extern "C" void kernel_launch(void* const* d_in, const int* in_sizes, int n_in,
                              void* d_out, int out_size, void* d_ws,
                              size_t ws_size, hipStream_t stream) {
    const float* x      = (const float*)d_in[0];
    const float* w_in   = (const float*)d_in[1];
    const float* b_in   = (const float*)d_in[2];
    const float* enc    = (const float*)d_in[3];
    const float* enc_v  = (const float*)d_in[4];
    const float* dec    = (const float*)d_in[5];
    const float* head_w = (const float*)d_in[6];
    const float* head_b = (const float*)d_in[7];
    float* out = (float*)d_out;

    // ---- workspace (~170 MB) ----
    char* w = (char*)d_ws;
    auto alloc = [&](size_t bytes) { void* p = (void*)w; w += bytes; return p; };
    unsigned short* w_inT = (unsigned short*)alloc((size_t)512 * 512 * 2);
    unsigned short* headT = (unsigned short*)alloc((size_t)512 * 512 * 2);
    unsigned short* encT  = (unsigned short*)alloc((size_t)NH_ * NL_ * D_ * 2);
    unsigned short* encvT = (unsigned short*)alloc((size_t)NH_ * NL_ * D_ * 2);
    unsigned short* decT  = (unsigned short*)alloc((size_t)D_ * HN_ * 2);
    unsigned short* xb    = (unsigned short*)alloc((size_t)BT_ * D_ * 2);
    float*          tmp   = (float*)alloc((size_t)4 * BT_ * D_ * 4);  // 4 K-slices
    float*          xsf0  = (float*)alloc((size_t)BT_ * D_ * 4);
    float*          xsf1  = (float*)alloc((size_t)BT_ * D_ * 4);
    unsigned short* xs_b  = (unsigned short*)alloc((size_t)BT_ * D_ * 2);
    unsigned short* xsT   = (unsigned short*)alloc((size_t)B_ * D_ * T_ * 2);
    unsigned short* xsp   = (unsigned short*)alloc((size_t)BT_ * HN_ * 2);
    unsigned short* qrh   = (unsigned short*)alloc((size_t)BT_ * HN_ * 2);
    unsigned short* qrT   = (unsigned short*)alloc((size_t)BT_ * HN_ * 2);
    unsigned short* Ct    = (unsigned short*)alloc((size_t)128 * 512 * 256 * 2); // 33.5 MB
    unsigned short* Sd    = (unsigned short*)alloc((size_t)128 * 256 * 256 * 2); // 16.8 MB
    unsigned short* ykv   = (unsigned short*)alloc((size_t)NH_ * BT_ * D_ * 2);
    float*          part  = (float*)alloc((size_t)256 * 4 * 128 * 2 * 4);        //  1 MB
    float*          csum  = (float*)alloc((size_t)HN_ * 4);                      //   8 KB
    const long SL = (long)BT_ * D_;   // split-K slice stride (elements)

    // ---- prep ----
    cast_b<<<BT_ * D_ / 1024, 256, 0, stream>>>(x, xb);
    trans_cast<<<dim3(16, 16, 1), 256, 0, stream>>>(w_in, 0, w_inT, 0, 512, 512);
    trans_cast<<<dim3(16, 16, 1), 256, 0, stream>>>(head_w, 0, headT, 0, 512, 512);
    trans_cast<<<dim3(8, 16, 8), 256, 0, stream>>>(enc, (long)D_ * NL_, encT,
                                                   (long)NL_ * D_, D_, NL_);
    trans_cast<<<dim3(8, 16, 8), 256, 0, stream>>>(enc_v, (long)D_ * NL_, encvT,
                                                   (long)NL_ * D_, D_, NL_);
    trans_cast<<<dim3(16, 64, 1), 256, 0, stream>>>(dec, 0, decT, 0, HN_, D_);
    colsum_k<<<HN_ / 4, 256, 0, stream>>>(encvT, csum);

    // ---- xs = LN(x @ w_in + b_in)  (split-K=4) ----
    gemm128<64, false, false, false, false>
        <<<dim3(4, 32, 4), 256, 0, stream>>>(xb, D_, 128, w_inT, D_, 128, tmp,
                                             D_, SL, nullptr, 128, nullptr,
                                             nullptr);
    ln_dual4<<<BT_, 256, 0, stream>>>(tmp, SL, b_in, xsf0, xs_b);

    float* xin = xsf0;
    float* xout = xsf1;
    for (int l = 0; l < 3; ++l) {
        // [enc_rope | xs_b->xsT transpose] merged (heavy blocks first)
        enc_tr<<<2560, 256, 0, stream>>>(xs_b, encT, xsp, qrh, qrT, xsT);
        // [ct_gemm | sdiag] merged (independent outputs)
        ct_sd<<<1408, 256, 0, stream>>>(xsT, qrT, qrh, Ct, Sd);
        // exclusive prefix over 8 chunks (in place)
        prefix_k<<<dim3(16, 64), 256, 0, stream>>>(Ct);
        // yKV(unnorm) = QR_i @ P + Sd-half @ X  + row stats
        pxg<<<dim3(16, 16, 4), 256, 0, stream>>>(qrh, Ct, Sd, xsT, ykv, part);
        // xy = relu(LN(yKV)[h] @ enc_v[h]) * x_sparse; LN folded via linearity,
        // (mu,inv) computed in-prologue from part (lnstats fold)
        gemm128<64, true, true, true, true>
            <<<dim3(2, 32, 8), 256, 0, stream>>>(
                ykv, D_, (long)BT_ * D_, encvT, D_, (long)NL_ * D_, xsp, HN_,
                NL_, xsp, 512, part, csum);
        // yMLP = xy @ decoder  (split-K=4) -> fp32 slices
        gemm128<64, false, false, false, false>
            <<<dim3(4, 32, 4), 256, 0, stream>>>(
                xsp, HN_, 512, decT, HN_, 512, tmp, D_, SL, nullptr, 512,
                nullptr, nullptr);
        // xs = LN(x_res + LN(yMLP))
        combine_dual4<<<BT_, 256, 0, stream>>>(tmp, SL, xin, xout, xs_b);
        float* t = xin; xin = xout; xout = t;
    }

    // logits = xs @ head_w + head_b  (split-K=4)
    gemm128<64, false, false, false, false>
        <<<dim3(4, 32, 4), 256, 0, stream>>>(xs_b, D_, 128, headT, D_, 128, tmp,
                                             D_, SL, nullptr, 128, nullptr,
                                             nullptr);
    add_out4<<<BT_ * 512 / 1024, 256, 0, stream>>>(tmp, SL, head_b, out);
}